// Round 13
// baseline (10039.598 us; speedup 1.0000x reference)
//
#include <hip/hip_runtime.h>
#include <hip/hip_bf16.h>

// Sizes (compile-time)
#define V 32000
#define E 1024
#define H 512
#define NL 2
#define B_ 32
#define S_ 128
#define TL_ 63

typedef __attribute__((ext_vector_type(8))) short short8;
typedef __attribute__((ext_vector_type(4))) float f32x4;

__device__ __forceinline__ float sigmoidf_(float x){ return 1.f/(1.f + __expf(-x)); }
__device__ __forceinline__ float fast_tanh(float x){ return 1.f - 2.f/(__expf(2.f*x) + 1.f); }
__device__ __forceinline__ ushort f2bf_(float f){
  uint u = __builtin_bit_cast(uint, f);
  uint r = (u + 0x7FFFu + ((u >> 16) & 1u)) >> 16;
  return (ushort)r;
}
// packed f32x2 -> bf16x2 (RNE), 1 VALU op (gfx950; guide T12)
__device__ __forceinline__ uint cvtpk(float lo, float hi){
  uint r;
  asm("v_cvt_pk_bf16_f32 %0, %1, %2" : "=v"(r) : "v"(lo), "v"(hi));
  return r;
}

// SYSTEM-scope (bypass L1+L2, ack at MALL) accessors for cross-block state.
__device__ __forceinline__ float aload(const float* p){
  return __hip_atomic_load(p, __ATOMIC_RELAXED, __HIP_MEMORY_SCOPE_SYSTEM);
}
__device__ __forceinline__ void astore(float* p, float v){
  __hip_atomic_store(p, v, __ATOMIC_RELAXED, __HIP_MEMORY_SCOPE_SYSTEM);
}

// fenceless grid barrier (R7-proven, flat): used for small zones (8-16 pollers).
__device__ __forceinline__ void gbar(uint* ctr, uint* gen, uint nblk, uint e){
  __syncthreads();
  if (threadIdx.x == 0){
    uint old = __hip_atomic_fetch_add(ctr, 1u, __ATOMIC_RELAXED, __HIP_MEMORY_SCOPE_SYSTEM);
    if (old == e*nblk - 1u){
      __hip_atomic_store(gen, e, __ATOMIC_RELAXED, __HIP_MEMORY_SCOPE_SYSTEM);
    } else {
      while (__hip_atomic_load(gen, __ATOMIC_RELAXED, __HIP_MEMORY_SCOPE_SYSTEM) < e)
        __builtin_amdgcn_s_sleep(2);
    }
  }
  __syncthreads();
}

// Mirrored-gen full-grid barrier (R12-proven): ctr isolated; 8 gen mirrors
// 128B apart; waiters poll mirror[bid&7] with s_sleep(32) backoff.
__device__ __forceinline__ void gbarM(uint* ctr, uint* mir, uint nblk, uint e, int myMir){
  __syncthreads();
  if (threadIdx.x == 0){
    uint old = __hip_atomic_fetch_add(ctr, 1u, __ATOMIC_RELAXED, __HIP_MEMORY_SCOPE_SYSTEM);
    if (old == e*nblk - 1u){
      #pragma unroll
      for (int m = 0; m < 8; m++)
        __hip_atomic_store(&mir[m*32], e, __ATOMIC_RELAXED, __HIP_MEMORY_SCOPE_SYSTEM);
    } else {
      while (__hip_atomic_load(&mir[myMir*32], __ATOMIC_RELAXED, __HIP_MEMORY_SCOPE_SYSTEM) < e)
        __builtin_amdgcn_s_sleep(32);
    }
  }
  __syncthreads();
}

// ---------------- embedding gathers ----------------
__global__ __launch_bounds__(256) void embed_enc(const int* __restrict__ ids,
                                                 const float* __restrict__ emb,
                                                 float* __restrict__ X0){
  int row = blockIdx.x;              // 0..4095 = s*32+b
  int s = row >> 5, b = row & 31;
  int tok = ids[b*S_ + s];
  const float4* src = (const float4*)(emb + (size_t)tok*E);
  float4* dst = (float4*)(X0 + (size_t)row*E);
  dst[threadIdx.x] = src[threadIdx.x];
}

__global__ __launch_bounds__(256) void embed_dec(const int* __restrict__ labels,
                                                 const float* __restrict__ emb,
                                                 float* __restrict__ Feat){
  int row = blockIdx.x;              // 0..2015 = t*32+b
  int t = row >> 5, b = row & 31;
  int tok = (t == 0) ? 1 : labels[b*TL_ + (t-1)];
  if (tok == -100) tok = 0;
  const float4* src = (const float4*)(emb + (size_t)tok*E);
  float4* dst = (float4*)(Feat + (size_t)row*2560 + 1536);
  dst[threadIdx.x] = src[threadIdx.x];
}

// ---------------- generic tiled f32 GEMM: C[M][N] = A[M][K] @ B[N][K]^T + bias[N] ----------------
__global__ __launch_bounds__(256) void gemm_f32(
    const float* __restrict__ A, int lda,
    const float* __restrict__ B, int ldb,
    const float* __restrict__ bias,
    float* __restrict__ C, int ldc,
    int M, int N, int K)
{
  __shared__ float As[8][132];
  __shared__ float Bs[8][132];
  int tid = threadIdx.x;
  int row0 = blockIdx.x*128, col0 = blockIdx.y*128;
  int lr = tid >> 1;
  int lk = (tid & 1) * 4;
  int ar = row0 + lr; if (ar > M-1) ar = M-1;
  const float* Ap = A + (size_t)ar*lda + lk;
  const float* Bp = B + (size_t)(col0 + lr)*ldb + lk;
  int tx = tid & 15, ty = tid >> 4;
  float acc[8][8];
  #pragma unroll
  for (int i=0;i<8;i++){
    #pragma unroll
    for (int j=0;j<8;j++) acc[i][j]=0.f;
  }
  for (int k0 = 0; k0 < K; k0 += 8){
    float4 a = *(const float4*)(Ap + k0);
    float4 b = *(const float4*)(Bp + k0);
    __syncthreads();
    As[lk+0][lr]=a.x; As[lk+1][lr]=a.y; As[lk+2][lr]=a.z; As[lk+3][lr]=a.w;
    Bs[lk+0][lr]=b.x; Bs[lk+1][lr]=b.y; Bs[lk+2][lr]=b.z; Bs[lk+3][lr]=b.w;
    __syncthreads();
    #pragma unroll
    for (int k=0;k<8;k++){
      float av[8], bv[8];
      *(float4*)&av[0] = *(const float4*)&As[k][ty*8];
      *(float4*)&av[4] = *(const float4*)&As[k][ty*8+4];
      *(float4*)&bv[0] = *(const float4*)&Bs[k][tx*8];
      *(float4*)&bv[4] = *(const float4*)&Bs[k][tx*8+4];
      #pragma unroll
      for (int i=0;i<8;i++){
        #pragma unroll
        for (int j=0;j<8;j++) acc[i][j] += av[i]*bv[j];
      }
    }
  }
  #pragma unroll
  for (int i=0;i<8;i++){
    int r = row0 + ty*8 + i;
    if (r < M){
      float* Cp = C + (size_t)r*ldc + col0 + tx*8;
      #pragma unroll
      for (int j=0;j<8;j++) Cp[j] = acc[i][j] + bias[col0 + tx*8 + j];
    }
  }
}

// ---------------- persistent encoder layer (zone-local barriers; R10-exact) ----------------
__global__ __launch_bounds__(256) void enc_layer(
    const float* __restrict__ GIf, const float* __restrict__ GIbk,
    const float* __restrict__ Whh, const float* __restrict__ bhh,
    const int* __restrict__ amask,
    float* __restrict__ hFa, float* __restrict__ hFb,
    float* __restrict__ hBa, float* __restrict__ hBb,
    float* __restrict__ Xout, uint* __restrict__ barbase)
{
  int dir  = blockIdx.x >> 7;
  int rr   = blockIdx.x & 127;
  int bg   = rr >> 4;
  int jblk = rr & 15;
  uint* z   = barbase + (size_t)(dir*8 + bg)*512;
  uint* ctr = z; uint* gen = z + 1;
  const float* GI = dir ? GIbk : GIf;
  const float* W  = Whh + (size_t)dir*1536*512;
  const float* bh = bhh + dir*1536;
  float* hA = dir ? hBa : hFa;
  float* hB = dir ? hBb : hFb;
  int tid = threadIdx.x;
  int bl = tid & 3, jl = (tid >> 2) & 31, kh = tid >> 7;
  int j = jblk*32 + jl;
  int b = bg*4 + bl;
  const float* w0 = W + (size_t)j*512        + kh*256;
  const float* w1 = W + (size_t)(j+512)*512  + kh*256;
  const float* w2 = W + (size_t)(j+1024)*512 + kh*256;
  float b0 = bh[j], b1 = bh[j+512], b2 = bh[j+1024];
  __shared__ float hS[4][512];   // this b-group's h, b-major: 8 KB
  __shared__ float red[256*3];
  uint e = 1;
  for (int step = 0; step < S_; step++){
    const float* hin = (step & 1) ? hB : hA;
    float*       hout= (step & 1) ? hA : hB;
    int t = dir ? (S_-1 - step) : step;
    for (int i = tid; i < 2048; i += 256){
      int bs = i >> 9, k = i & 511;
      hS[bs][k] = aload(hin + (size_t)(bg*4 + bs)*512 + k);
    }
    __syncthreads();
    float s0=0.f, s1=0.f, s2=0.f;
    #pragma unroll 8
    for (int k=0;k<256;k+=4){
      float x0 = hS[bl][kh*256 + k];
      float x1 = hS[bl][kh*256 + k + 1];
      float x2 = hS[bl][kh*256 + k + 2];
      float x3 = hS[bl][kh*256 + k + 3];
      float4 v0 = *(const float4*)(w0+k);
      float4 v1 = *(const float4*)(w1+k);
      float4 v2 = *(const float4*)(w2+k);
      s0 += x0*v0.x + x1*v0.y + x2*v0.z + x3*v0.w;
      s1 += x0*v1.x + x1*v1.y + x2*v1.z + x3*v1.w;
      s2 += x0*v2.x + x1*v2.y + x2*v2.z + x3*v2.w;
    }
    red[tid*3+0]=s0; red[tid*3+1]=s1; red[tid*3+2]=s2;
    __syncthreads();
    if (kh == 0){
      float sr = s0 + red[(tid+128)*3+0];
      float sz = s1 + red[(tid+128)*3+1];
      float sn = s2 + red[(tid+128)*3+2];
      const float* gi = GI + ((size_t)t*32 + b)*1536;
      float r = sigmoidf_(gi[j]      + sr + b0);
      float z_ = sigmoidf_(gi[j+512]  + sz + b1);
      float n = fast_tanh(gi[j+1024] + r*(sn + b2));
      float hold = hS[bl][j];
      float hn = (1.f - z_)*n + z_*hold;
      int m = amask[b*S_ + t];
      astore(hout + (size_t)b*512 + j, m ? hn : hold);
      Xout[((size_t)t*32 + b)*1024 + dir*512 + j] = m ? hn : 0.f;
    }
    gbar(ctr, gen, 16, e); e++;
  }
}

// fc init: reads B-MAJOR encoder finals, writes K-MAJOR decoder h slot-0
__global__ __launch_bounds__(256) void fc_init(
    const float* __restrict__ hF, const float* __restrict__ hB,
    const float* __restrict__ fcW, const float* __restrict__ fcb,
    float* __restrict__ h0T, float* __restrict__ h1T)
{
  int idx = blockIdx.x*256 + threadIdx.x;  // 0..32767
  int l = idx >> 14;
  int b = (idx >> 9) & 31;
  int jj = idx & 511;
  const float* w = fcW + ((size_t)(l*512 + jj))*1024;
  const float* hf = hF + (size_t)b*512;
  const float* hb = hB + (size_t)b*512;
  float s = fcb[l*512 + jj];
  #pragma unroll 4
  for (int k=0;k<512;k+=4){
    float4 wv = *(const float4*)(w+k);
    s += hf[k+0]*wv.x + hf[k+1]*wv.y + hf[k+2]*wv.z + hf[k+3]*wv.w;
    float4 wv2 = *(const float4*)(w+512+k);
    s += hb[k+0]*wv2.x + hb[k+1]*wv2.y + hb[k+2]*wv2.z + hb[k+3]*wv2.w;
  }
  __hip_atomic_store(&(l ? h1T : h0T)[jj*32 + b], fast_tanh(s),
                     __ATOMIC_RELAXED, __HIP_MEMORY_SCOPE_SYSTEM);
}

// ---------------- persistent decoder loop (R12-exact) ----------------
__global__ __launch_bounds__(256) void dec_loop(
    const float* __restrict__ ENC,  const float* __restrict__ Eenc,
    const float* __restrict__ aW,   const float* __restrict__ av,
    const int* __restrict__ amask,
    const float* __restrict__ GI0,  const float* __restrict__ Wih0,
    const float* __restrict__ Wihr, const float* __restrict__ Whh,
    const float* __restrict__ bih,  const float* __restrict__ bhh,
    float* __restrict__ h0R, float* __restrict__ h1R,
    float* __restrict__ wgtR, float* __restrict__ partR,
    float* __restrict__ Feat, uint* __restrict__ barbase)
{
  uint* ctr = barbase;            // isolated line
  uint* mir = barbase + 64;       // 8 mirrors, 128B apart
  __shared__ float eeS[128*64];    // Eenc slice, 32 KB
  __shared__ float encS[128*128];  // ENC slice, 64 KB
  __shared__ float sm[1600];
  int tid = threadIdx.x;
  int bid = blockIdx.x;
  int myMir = bid & 7;
  const float* Whh1 = Whh + (size_t)1536*512;
  const float* bih1 = bih + 1536;
  const float* bhh1 = bhh + 1536;
  uint ef = 1;
  uint ez = 1;

  int bP = bid >> 3, kg = bid & 7;
  uint* zctr = barbase + 1024 + bP*32;
  uint* zgen = zctr + 1;
  int wv = tid >> 6, ln = tid & 63;
  int jl2 = tid & 127, kh2 = tid >> 7;
  int jcol = kg*128 + jl2;

  for (int i = tid; i < 128*64; i += 256){
    int s = i >> 6, kk = i & 63;
    eeS[i] = Eenc[((size_t)s*32 + bP)*512 + kg*64 + kk];
  }
  for (int i = tid; i < 128*128; i += 256){
    int s = i >> 7, j2 = i & 127;
    encS[i] = ENC[((size_t)s*32 + bP)*1024 + kg*128 + j2];
  }
  __syncthreads();

  for (int t = 0; t < TL_; t++){
    const float* h0cur = h0R + (size_t)t*16384;
    float*       h0nxt = h0R + (size_t)(t+1)*16384;
    const float* h1cur = h1R + (size_t)t*16384;
    float*       h1nxt = h1R + (size_t)(t+1)*16384;
    float*       wgtT  = wgtR + (size_t)t*32768;
    float*       part  = partR + (size_t)t*32768;

    // ---- P1
    {
      float hreg[8];
      #pragma unroll
      for (int q=0;q<8;q++) hreg[q] = h1cur[(ln*8+q)*32 + bP];
      float avreg = av[kg*64 + ln];
      float* pre_s = sm;  // [64]
      #pragma unroll 4
      for (int i=0;i<16;i++){
        int k = kg*64 + wv*16 + i;
        const float* wr = aW + (size_t)k*1536 + ln*8;
        float4 u0 = *(const float4*)wr;
        float4 u1 = *(const float4*)(wr+4);
        float p = u0.x*hreg[0]+u0.y*hreg[1]+u0.z*hreg[2]+u0.w*hreg[3]
                + u1.x*hreg[4]+u1.y*hreg[5]+u1.z*hreg[6]+u1.w*hreg[7];
        #pragma unroll
        for (int off=32; off>0; off>>=1) p += __shfl_xor(p, off);
        if (ln == i) pre_s[wv*16+i] = p;
      }
      __syncthreads();
      float myPre = pre_s[ln];
      for (int si=0; si<32; si++){
        int s = wv*32 + si;
        float ee = eeS[s*64 + ln];
        float v = fast_tanh(myPre + ee) * avreg;
        #pragma unroll
        for (int off=32; off>0; off>>=1) v += __shfl_xor(v, off);
        if (ln == 0) astore(&part[(bP*8+kg)*128 + s], v);
      }
    }
    gbar(zctr, zgen, 8, ez); ez++;

    // ---- P2
    {
      float* praw = sm;         // [1024]
      float* sa   = sm + 1024;  // [128]
      float* aw   = sm + 1152;  // [128]
      float* red2 = sm + 1280;  // [256]
      float* sv   = sm + 1536;  // [1]
      #pragma unroll
      for (int q=0;q<4;q++) praw[tid*4+q] = part[bP*1024 + tid*4+q];
      __syncthreads();
      if (tid < 128){
        float s8 = 0.f;
        #pragma unroll
        for (int kg2=0;kg2<8;kg2++) s8 += praw[kg2*128 + tid];
        sa[tid] = amask[bP*S_ + tid] ? s8 : -1e10f;
      }
      __syncthreads();
      if (tid < 64){
        float m0 = fmaxf(sa[tid], sa[tid+64]);
        #pragma unroll
        for (int off=32; off>0; off>>=1) m0 = fmaxf(m0, __shfl_xor(m0, off));
        float e0 = __expf(sa[tid]-m0), e1 = __expf(sa[tid+64]-m0);
        aw[tid] = e0; aw[tid+64] = e1;
        float ss = e0 + e1;
        #pragma unroll
        for (int off=32; off>0; off>>=1) ss += __shfl_xor(ss, off);
        if (tid == 0) sv[0] = ss;
      }
      __syncthreads();
      float inv = 1.f / sv[0];
      float p = 0.f;
      #pragma unroll
      for (int s=0;s<64;s++) p += aw[kh2*64+s] * encS[(kh2*64+s)*128 + jl2];
      red2[jl2*2+kh2] = p;
      __syncthreads();
      if (kh2 == 0){
        float wvv = (red2[jl2*2] + red2[jl2*2+1]) * inv;
        astore(&wgtT[jcol*32 + bP], wvv);
        Feat[((size_t)t*32 + bP)*2560 + 512 + jcol] = wvv;
      }
    }
    gbarM(ctr, mir, 256, ef, myMir); ef++;

    // ---- P3
    {
      int b = tid & 31, kq = (tid >> 5) & 3, jl = tid >> 7;
      int jj = bid*2 + jl;
      const float* u0 = Wih0 + (size_t)jj*2048        + 1024 + kq*256;
      const float* u1 = Wih0 + (size_t)(jj+512)*2048  + 1024 + kq*256;
      const float* u2 = Wih0 + (size_t)(jj+1024)*2048 + 1024 + kq*256;
      const float* xT = wgtT + (size_t)(kq*256)*32 + b;
      float a0=0.f, a1=0.f, a2=0.f;
      #pragma unroll 8
      for (int k=0;k<256;k+=4){
        float x0=xT[(k+0)*32], x1=xT[(k+1)*32];
        float x2=xT[(k+2)*32], x3=xT[(k+3)*32];
        float4 v0=*(const float4*)(u0+k);
        float4 v1=*(const float4*)(u1+k);
        float4 v2=*(const float4*)(u2+k);
        a0 += x0*v0.x + x1*v0.y + x2*v0.z + x3*v0.w;
        a1 += x0*v1.x + x1*v1.y + x2*v1.z + x3*v1.w;
        a2 += x0*v2.x + x1*v2.y + x2*v2.z + x3*v2.w;
      }
      const float* w0 = Whh + (size_t)jj*512        + kq*128;
      const float* w1 = Whh + (size_t)(jj+512)*512  + kq*128;
      const float* w2 = Whh + (size_t)(jj+1024)*512 + kq*128;
      const float* hT = h0cur + (size_t)(kq*128)*32 + b;
      float s0=0.f, s1=0.f, s2=0.f;
      #pragma unroll 8
      for (int k=0;k<128;k+=4){
        float x0=hT[(k+0)*32], x1=hT[(k+1)*32];
        float x2=hT[(k+2)*32], x3=hT[(k+3)*32];
        float4 v0=*(const float4*)(w0+k);
        float4 v1=*(const float4*)(w1+k);
        float4 v2=*(const float4*)(w2+k);
        s0 += x0*v0.x + x1*v0.y + x2*v0.z + x3*v0.w;
        s1 += x0*v1.x + x1*v1.y + x2*v1.z + x3*v1.w;
        s2 += x0*v2.x + x1*v2.y + x2*v2.z + x3*v2.w;
      }
      float* red = sm;
      int ridx = ((jl*4 + kq)*32 + b)*4;
      red[ridx+0] = a0 + s0;
      red[ridx+1] = a1 + s1;
      red[ridx+2] = a2;
      red[ridx+3] = s2;
      __syncthreads();
      if (kq == 0){
        float P0=0.f, P1=0.f, P2=0.f, P3=0.f;
        #pragma unroll
        for (int q=0;q<4;q++){
          int ri = ((jl*4 + q)*32 + b)*4;
          P0 += red[ri+0]; P1 += red[ri+1]; P2 += red[ri+2]; P3 += red[ri+3];
        }
        const float* gi = GI0 + ((size_t)t*32 + b)*1536;
        float r = sigmoidf_(gi[jj]      + P0 + bhh[jj]);
        float z_ = sigmoidf_(gi[jj+512]  + P1 + bhh[jj+512]);
        float n = fast_tanh(gi[jj+1024] + P2 + r*(P3 + bhh[jj+1024]));
        float hold = h0cur[jj*32 + b];
        astore(h0nxt + jj*32 + b, (1.f - z_)*n + z_*hold);
      }
    }
    gbarM(ctr, mir, 256, ef, myMir); ef++;

    // ---- P4
    {
      int b = tid & 31, kq = (tid >> 5) & 3, jl = tid >> 7;
      int jj = bid*2 + jl;
      const float* i0 = Wihr + (size_t)jj*512        + kq*128;
      const float* i1 = Wihr + (size_t)(jj+512)*512  + kq*128;
      const float* i2 = Wihr + (size_t)(jj+1024)*512 + kq*128;
      const float* xT = h0nxt + (size_t)(kq*128)*32 + b;
      float a0=0.f, a1=0.f, a2=0.f;
      #pragma unroll 8
      for (int k=0;k<128;k+=4){
        float x0=xT[(k+0)*32], x1=xT[(k+1)*32];
        float x2=xT[(k+2)*32], x3=xT[(k+3)*32];
        float4 v0=*(const float4*)(i0+k);
        float4 v1=*(const float4*)(i1+k);
        float4 v2=*(const float4*)(i2+k);
        a0 += x0*v0.x + x1*v0.y + x2*v0.z + x3*v0.w;
        a1 += x0*v1.x + x1*v1.y + x2*v1.z + x3*v1.w;
        a2 += x0*v2.x + x1*v2.y + x2*v2.z + x3*v2.w;
      }
      const float* w0 = Whh1 + (size_t)jj*512        + kq*128;
      const float* w1 = Whh1 + (size_t)(jj+512)*512  + kq*128;
      const float* w2 = Whh1 + (size_t)(jj+1024)*512 + kq*128;
      const float* hT = h1cur + (size_t)(kq*128)*32 + b;
      float s0=0.f, s1=0.f, s2=0.f;
      #pragma unroll 8
      for (int k=0;k<128;k+=4){
        float x0=hT[(k+0)*32], x1=hT[(k+1)*32];
        float x2=hT[(k+2)*32], x3=hT[(k+3)*32];
        float4 v0=*(const float4*)(w0+k);
        float4 v1=*(const float4*)(w1+k);
        float4 v2=*(const float4*)(w2+k);
        s0 += x0*v0.x + x1*v0.y + x2*v0.z + x3*v0.w;
        s1 += x0*v1.x + x1*v1.y + x2*v1.z + x3*v1.w;
        s2 += x0*v2.x + x1*v2.y + x2*v2.z + x3*v2.w;
      }
      float* red = sm;
      int ridx = ((jl*4 + kq)*32 + b)*4;
      red[ridx+0] = a0 + s0;
      red[ridx+1] = a1 + s1;
      red[ridx+2] = a2;
      red[ridx+3] = s2;
      __syncthreads();
      if (kq == 0){
        float P0=0.f, P1=0.f, P2=0.f, P3=0.f;
        #pragma unroll
        for (int q=0;q<4;q++){
          int ri = ((jl*4 + q)*32 + b)*4;
          P0 += red[ri+0]; P1 += red[ri+1]; P2 += red[ri+2]; P3 += red[ri+3];
        }
        float r = sigmoidf_(P0 + bih1[jj]      + bhh1[jj]);
        float z_ = sigmoidf_(P1 + bih1[jj+512]  + bhh1[jj+512]);
        float n = fast_tanh(P2 + bih1[jj+1024] + r*(P3 + bhh1[jj+1024]));
        float hold = h1cur[jj*32 + b];
        float hn = (1.f - z_)*n + z_*hold;
        astore(h1nxt + jj*32 + b, hn);
        Feat[((size_t)t*32 + b)*2560 + jj] = hn;
      }
    }
    gbarM(ctr, mir, 256, ef, myMir); ef++;
  }
}

// zero the t=0 plane of out
__global__ __launch_bounds__(256) void zero_t0(float* __restrict__ out){
  int idx = blockIdx.x*256 + threadIdx.x;
  if (idx < 32*V){
    int b = idx / V, v = idx - b*V;
    out[(size_t)b*64*V + v] = 0.f;
  }
}

// ---------------- bf16 MFMA output GEMM ----------------
// 1D grid 4000 (16 row-blocks x 250 col-blocks), XCD-swizzled so the 16
// blocks sharing a B-panel co-locate on one XCD (outW streamed ~once).
// f32->bf16 conversion via packed v_cvt_pk_bf16_f32 (16 VALU/thread/iter
// instead of 96 with the scalar RNE bit-twiddle).
__global__ __launch_bounds__(256) void out_gemm(
    const float* __restrict__ A,    // Feat [2016][2560]
    const float* __restrict__ Bw,   // out_W [32000][2560]
    const float* __restrict__ bias, // out_b [32000]
    float* __restrict__ out)        // [32][64][32000]
{
  __shared__ ushort As[4][129][8];
  __shared__ ushort Bs[4][129][8];
  int tid = threadIdx.x;
  int lane = tid & 63, wid = tid >> 6;
  // bijective XCD swizzle: 4000 % 8 == 0
  int orig = ((int)blockIdx.x & 7)*500 + ((int)blockIdx.x >> 3);
  int row0 = (orig & 15)*128, col0 = (orig >> 4)*128;
  int sr = tid >> 1;
  int s0 = (tid & 1) * 2;
  int sk = (tid & 1) * 16;
  int arow = row0 + sr; if (arow > 2015) arow = 2015;
  const float* Ap = A + (size_t)arow*2560 + sk;
  const float* Bp = Bw + (size_t)(col0 + sr)*2560 + sk;
  int wr = (wid >> 1)*64, wc = (wid & 1)*64;
  int fr = lane & 15, slot = lane >> 4;
  f32x4 acc[4][4];
  #pragma unroll
  for (int m=0;m<4;m++){
    #pragma unroll
    for (int n=0;n<4;n++) acc[m][n] = (f32x4){0.f,0.f,0.f,0.f};
  }
  for (int k0 = 0; k0 < 2560; k0 += 32){
    float4 a0 = *(const float4*)(Ap + k0);
    float4 a1 = *(const float4*)(Ap + k0 + 4);
    float4 a2 = *(const float4*)(Ap + k0 + 8);
    float4 a3 = *(const float4*)(Ap + k0 + 12);
    float4 b0 = *(const float4*)(Bp + k0);
    float4 b1 = *(const float4*)(Bp + k0 + 4);
    float4 b2 = *(const float4*)(Bp + k0 + 8);
    float4 b3 = *(const float4*)(Bp + k0 + 12);
    __syncthreads();
    uint4 ua, ua2, ub, ub2;
    ua.x  = cvtpk(a0.x, a0.y); ua.y  = cvtpk(a0.z, a0.w);
    ua.z  = cvtpk(a1.x, a1.y); ua.w  = cvtpk(a1.z, a1.w);
    ua2.x = cvtpk(a2.x, a2.y); ua2.y = cvtpk(a2.z, a2.w);
    ua2.z = cvtpk(a3.x, a3.y); ua2.w = cvtpk(a3.z, a3.w);
    ub.x  = cvtpk(b0.x, b0.y); ub.y  = cvtpk(b0.z, b0.w);
    ub.z  = cvtpk(b1.x, b1.y); ub.w  = cvtpk(b1.z, b1.w);
    ub2.x = cvtpk(b2.x, b2.y); ub2.y = cvtpk(b2.z, b2.w);
    ub2.z = cvtpk(b3.x, b3.y); ub2.w = cvtpk(b3.z, b3.w);
    *(uint4*)&As[s0  ][sr][0] = ua;
    *(uint4*)&As[s0+1][sr][0] = ua2;
    *(uint4*)&Bs[s0  ][sr][0] = ub;
    *(uint4*)&Bs[s0+1][sr][0] = ub2;
    __syncthreads();
    short8 af[4], bfr[4];
    #pragma unroll
    for (int m=0;m<4;m++) af[m]  = *(const short8*)&As[slot][wr + m*16 + fr][0];
    #pragma unroll
    for (int n=0;n<4;n++) bfr[n] = *(const short8*)&Bs[slot][wc + n*16 + fr][0];
    #pragma unroll
    for (int m=0;m<4;m++){
      #pragma unroll
      for (int n=0;n<4;n++)
        acc[m][n] = __builtin_amdgcn_mfma_f32_16x16x32_bf16(af[m], bfr[n], acc[m][n], 0, 0, 0);
    }
  }
  int cb = lane & 15, rb = (lane >> 4)*4;
  #pragma unroll
  for (int m=0;m<4;m++){
    #pragma unroll
    for (int n=0;n<4;n++){
      int c = col0 + wc + n*16 + cb;
      float bi = bias[c];
      #pragma unroll
      for (int j=0;j<4;j++){
        int r = row0 + wr + m*16 + rb + j;
        if (r < 2016){
          int bb = r & 31, tt = r >> 5;
          out[((size_t)bb*64 + tt + 1)*V + c] = acc[m][n][j] + bi;
        }
      }
    }
  }
}

extern "C" void kernel_launch(void* const* d_in, const int* in_sizes, int n_in,
                              void* d_out, int out_size, void* d_ws, size_t ws_size,
                              hipStream_t stream) {
  (void)in_sizes; (void)n_in; (void)out_size; (void)ws_size;
  const int*   ids    = (const int*)d_in[0];
  const int*   amask  = (const int*)d_in[1];
  const int*   labels = (const int*)d_in[2];
  const float* enc_emb= (const float*)d_in[3];
  const float* eWih   = (const float*)d_in[4];
  const float* eWhh   = (const float*)d_in[5];
  const float* ebih   = (const float*)d_in[6];
  const float* ebhh   = (const float*)d_in[7];
  const float* fcW    = (const float*)d_in[8];
  const float* fcb    = (const float*)d_in[9];
  const float* aW     = (const float*)d_in[10];
  const float* ab     = (const float*)d_in[11];
  const float* av     = (const float*)d_in[12];
  const float* dec_emb= (const float*)d_in[13];
  const float* dWih0  = (const float*)d_in[14];
  const float* dWihr  = (const float*)d_in[15];
  const float* dWhh   = (const float*)d_in[16];
  const float* dbih   = (const float*)d_in[17];
  const float* dbhh   = (const float*)d_in[18];
  const float* outW   = (const float*)d_in[19];
  const float* outb   = (const float*)d_in[20];
  float* out = (float*)d_out;

  // barrier zones: enc layer l zone (dir,bg) at bar + l*8192 + (dir*8+bg)*512
  // (16384 uints); dec at bar + 16384: ctr@0, mirrors@64..288, bP zones@1024+.
  uint*  bar = (uint*)d_ws;
  float* ws  = (float*)d_ws + 20480;
  float* X0  = ws;
  float* X1  = X0  + (size_t)4096*1024;
  float* ENC = X1  + (size_t)4096*1024;
  float* GIa = ENC + (size_t)4096*1024;
  float* GIb = GIa + (size_t)4096*1536;
  float* Eenc= GIb + (size_t)4096*1536;
  float* GI0 = Eenc+ (size_t)4096*512;
  float* Feat= GI0 + (size_t)2016*1536;
  float* hp  = Feat+ (size_t)2016*2560;
  float* hFa = hp;             float* hFb = hFa + 32*512;
  float* hBa = hFb + 32*512;   float* hBb = hBa + 32*512;
  // rotating decoder buffers live in the X0/X1 regions (dead by decoder time)
  float* wgtR  = X0;                          // 63 * 32768
  float* partR = X0 + (size_t)63*32768;       // 63 * 32768
  float* h0R   = X1;                          // 64 * 16384
  float* h1R   = X1 + (size_t)64*16384;       // 64 * 16384

  hipMemsetAsync(bar, 0, 20480*sizeof(uint), stream);

  // ---- encoder ----
  embed_enc<<<4096, 256, 0, stream>>>(ids, enc_emb, X0);
  for (int l = 0; l < NL; l++){
    const float* Xin = l ? X1 : X0;
    float* Xout = l ? ENC : X1;
    hipMemsetAsync(hFa, 0, 32*512*sizeof(float), stream);
    hipMemsetAsync(hBa, 0, 32*512*sizeof(float), stream);
    gemm_f32<<<dim3(32,12),256,0,stream>>>(Xin, 1024, eWih + (size_t)(l*2+0)*1536*1024, 1024,
        ebih + (l*2+0)*1536, GIa, 1536, 4096, 1536, 1024);
    gemm_f32<<<dim3(32,12),256,0,stream>>>(Xin, 1024, eWih + (size_t)(l*2+1)*1536*1024, 1024,
        ebih + (l*2+1)*1536, GIb, 1536, 4096, 1536, 1024);
    {
      const float* gia = GIa; const float* gib = GIb;
      const float* whhp = eWhh + (size_t)l*2*1536*512;
      const float* bhhp = ebhh + (size_t)l*2*1536;
      uint* eb = bar + (size_t)l*8192;
      void* args[] = {(void*)&gia, (void*)&gib, (void*)&whhp, (void*)&bhhp,
                      (void*)&amask, (void*)&hFa, (void*)&hFb, (void*)&hBa,
                      (void*)&hBb, (void*)&Xout, (void*)&eb};
      hipLaunchCooperativeKernel((const void*)enc_layer, dim3(256), dim3(256), args, 0, stream);
    }
  }
  // ---- decoder setup ----
  fc_init<<<128,256,0,stream>>>(hFa, hBa, fcW, fcb, h0R, h1R);
  gemm_f32<<<dim3(32,4),256,0,stream>>>(ENC, 1024, aW + 512, 1536, ab, Eenc, 512, 4096, 512, 1024);
  embed_dec<<<2016,256,0,stream>>>(labels, dec_emb, Feat);
  gemm_f32<<<dim3(16,12),256,0,stream>>>(Feat + 1536, 2560, dWih0, 2048, dbih, GI0, 1536, 2016, 1536, 1024);
  // ---- decoder loop ----
  {
    const float* encp = ENC; const float* eencp = Eenc; const float* gi0p = GI0;
    float* featp = Feat;
    uint* db = bar + 16384;
    void* args[] = {(void*)&encp, (void*)&eencp, (void*)&aW, (void*)&av,
                    (void*)&amask, (void*)&gi0p, (void*)&dWih0, (void*)&dWihr,
                    (void*)&dWhh, (void*)&dbih, (void*)&dbhh,
                    (void*)&h0R, (void*)&h1R, (void*)&wgtR, (void*)&partR,
                    (void*)&featp, (void*)&db};
    hipLaunchCooperativeKernel((const void*)dec_loop, dim3(256), dim3(256), args, 0, stream);
  }
  // ---- output ----
  zero_t0<<<4000,256,0,stream>>>(out);
  out_gemm<<<4000,256,0,stream>>>(Feat, outW, outb, out);
}

// Round 14
// 9149.873 us; speedup vs baseline: 1.0972x; 1.0972x over previous
//
#include <hip/hip_runtime.h>
#include <hip/hip_bf16.h>

// Sizes (compile-time)
#define V 32000
#define E 1024
#define H 512
#define NL 2
#define B_ 32
#define S_ 128
#define TL_ 63

typedef __attribute__((ext_vector_type(8))) short short8;
typedef __attribute__((ext_vector_type(4))) float f32x4;

__device__ __forceinline__ float sigmoidf_(float x){ return 1.f/(1.f + __expf(-x)); }
__device__ __forceinline__ float fast_tanh(float x){ return 1.f - 2.f/(__expf(2.f*x) + 1.f); }
// packed f32x2 -> bf16x2 (RNE), 1 VALU op (gfx950)
__device__ __forceinline__ uint cvtpk(float lo, float hi){
  uint r;
  asm("v_cvt_pk_bf16_f32 %0, %1, %2" : "=v"(r) : "v"(lo), "v"(hi));
  return r;
}

// SYSTEM-scope (bypass L1+L2, ack at MALL) accessors for cross-block state.
__device__ __forceinline__ float aload(const float* p){
  return __hip_atomic_load(p, __ATOMIC_RELAXED, __HIP_MEMORY_SCOPE_SYSTEM);
}
__device__ __forceinline__ void astore(float* p, float v){
  __hip_atomic_store(p, v, __ATOMIC_RELAXED, __HIP_MEMORY_SCOPE_SYSTEM);
}

// fenceless grid barrier (R7-proven, flat): used for small zones (8-16 pollers).
__device__ __forceinline__ void gbar(uint* ctr, uint* gen, uint nblk, uint e){
  __syncthreads();
  if (threadIdx.x == 0){
    uint old = __hip_atomic_fetch_add(ctr, 1u, __ATOMIC_RELAXED, __HIP_MEMORY_SCOPE_SYSTEM);
    if (old == e*nblk - 1u){
      __hip_atomic_store(gen, e, __ATOMIC_RELAXED, __HIP_MEMORY_SCOPE_SYSTEM);
    } else {
      while (__hip_atomic_load(gen, __ATOMIC_RELAXED, __HIP_MEMORY_SCOPE_SYSTEM) < e)
        __builtin_amdgcn_s_sleep(2);
    }
  }
  __syncthreads();
}

// Mirrored-gen full-grid barrier (R12-proven): ctr isolated; 8 gen mirrors
// 128B apart; waiters poll mirror[bid&7] with s_sleep(32) backoff.
__device__ __forceinline__ void gbarM(uint* ctr, uint* mir, uint nblk, uint e, int myMir){
  __syncthreads();
  if (threadIdx.x == 0){
    uint old = __hip_atomic_fetch_add(ctr, 1u, __ATOMIC_RELAXED, __HIP_MEMORY_SCOPE_SYSTEM);
    if (old == e*nblk - 1u){
      #pragma unroll
      for (int m = 0; m < 8; m++)
        __hip_atomic_store(&mir[m*32], e, __ATOMIC_RELAXED, __HIP_MEMORY_SCOPE_SYSTEM);
    } else {
      while (__hip_atomic_load(&mir[myMir*32], __ATOMIC_RELAXED, __HIP_MEMORY_SCOPE_SYSTEM) < e)
        __builtin_amdgcn_s_sleep(32);
    }
  }
  __syncthreads();
}

// ---------------- embedding gathers ----------------
__global__ __launch_bounds__(256) void embed_enc(const int* __restrict__ ids,
                                                 const float* __restrict__ emb,
                                                 float* __restrict__ X0){
  int row = blockIdx.x;              // 0..4095 = s*32+b
  int s = row >> 5, b = row & 31;
  int tok = ids[b*S_ + s];
  const float4* src = (const float4*)(emb + (size_t)tok*E);
  float4* dst = (float4*)(X0 + (size_t)row*E);
  dst[threadIdx.x] = src[threadIdx.x];
}

__global__ __launch_bounds__(256) void embed_dec(const int* __restrict__ labels,
                                                 const float* __restrict__ emb,
                                                 float* __restrict__ Feat){
  int row = blockIdx.x;              // 0..2015 = t*32+b
  int t = row >> 5, b = row & 31;
  int tok = (t == 0) ? 1 : labels[b*TL_ + (t-1)];
  if (tok == -100) tok = 0;
  const float4* src = (const float4*)(emb + (size_t)tok*E);
  float4* dst = (float4*)(Feat + (size_t)row*2560 + 1536);
  dst[threadIdx.x] = src[threadIdx.x];
}

// ---------------- bf16 MFMA GEMM: C[M][N] = A[M][K] @ B[N][K]^T + bias[N] ----------------
// Generalized from the verified out_gemm: 128x128 tile, BK=32, 4 waves,
// cvtpk f32->bf16 staging into [4][129][8] LDS (conflict-mitigated).
// Requires: K % 32 == 0, N % 128 == 0; M handled via clamp+guard.
__global__ __launch_bounds__(256) void gemm_bf16(
    const float* __restrict__ A, int lda,
    const float* __restrict__ B, int ldb,
    const float* __restrict__ bias,
    float* __restrict__ C, int ldc,
    int M, int N, int K)
{
  __shared__ ushort As[4][129][8];
  __shared__ ushort Bs[4][129][8];
  int tid = threadIdx.x;
  int lane = tid & 63, wid = tid >> 6;
  int row0 = blockIdx.x*128, col0 = blockIdx.y*128;
  int sr = tid >> 1;
  int s0 = (tid & 1) * 2;
  int sk = (tid & 1) * 16;
  int arow = row0 + sr; if (arow > M-1) arow = M-1;
  const float* Ap = A + (size_t)arow*lda + sk;
  const float* Bp = B + (size_t)(col0 + sr)*ldb + sk;
  int wr = (wid >> 1)*64, wc = (wid & 1)*64;
  int fr = lane & 15, slot = lane >> 4;
  f32x4 acc[4][4];
  #pragma unroll
  for (int m=0;m<4;m++){
    #pragma unroll
    for (int n=0;n<4;n++) acc[m][n] = (f32x4){0.f,0.f,0.f,0.f};
  }
  for (int k0 = 0; k0 < K; k0 += 32){
    float4 a0 = *(const float4*)(Ap + k0);
    float4 a1 = *(const float4*)(Ap + k0 + 4);
    float4 a2 = *(const float4*)(Ap + k0 + 8);
    float4 a3 = *(const float4*)(Ap + k0 + 12);
    float4 b0 = *(const float4*)(Bp + k0);
    float4 b1 = *(const float4*)(Bp + k0 + 4);
    float4 b2 = *(const float4*)(Bp + k0 + 8);
    float4 b3 = *(const float4*)(Bp + k0 + 12);
    __syncthreads();
    uint4 ua, ua2, ub, ub2;
    ua.x  = cvtpk(a0.x, a0.y); ua.y  = cvtpk(a0.z, a0.w);
    ua.z  = cvtpk(a1.x, a1.y); ua.w  = cvtpk(a1.z, a1.w);
    ua2.x = cvtpk(a2.x, a2.y); ua2.y = cvtpk(a2.z, a2.w);
    ua2.z = cvtpk(a3.x, a3.y); ua2.w = cvtpk(a3.z, a3.w);
    ub.x  = cvtpk(b0.x, b0.y); ub.y  = cvtpk(b0.z, b0.w);
    ub.z  = cvtpk(b1.x, b1.y); ub.w  = cvtpk(b1.z, b1.w);
    ub2.x = cvtpk(b2.x, b2.y); ub2.y = cvtpk(b2.z, b2.w);
    ub2.z = cvtpk(b3.x, b3.y); ub2.w = cvtpk(b3.z, b3.w);
    *(uint4*)&As[s0  ][sr][0] = ua;
    *(uint4*)&As[s0+1][sr][0] = ua2;
    *(uint4*)&Bs[s0  ][sr][0] = ub;
    *(uint4*)&Bs[s0+1][sr][0] = ub2;
    __syncthreads();
    short8 af[4], bfr[4];
    #pragma unroll
    for (int m=0;m<4;m++) af[m]  = *(const short8*)&As[slot][wr + m*16 + fr][0];
    #pragma unroll
    for (int n=0;n<4;n++) bfr[n] = *(const short8*)&Bs[slot][wc + n*16 + fr][0];
    #pragma unroll
    for (int m=0;m<4;m++){
      #pragma unroll
      for (int n=0;n<4;n++)
        acc[m][n] = __builtin_amdgcn_mfma_f32_16x16x32_bf16(af[m], bfr[n], acc[m][n], 0, 0, 0);
    }
  }
  int cb = lane & 15, rb = (lane >> 4)*4;
  #pragma unroll
  for (int m=0;m<4;m++){
    #pragma unroll
    for (int n=0;n<4;n++){
      int c = col0 + wc + n*16 + cb;
      float bi = bias[c];
      #pragma unroll
      for (int j=0;j<4;j++){
        int r = row0 + wr + m*16 + rb + j;
        if (r < M){
          C[(size_t)r*ldc + c] = acc[m][n][j] + bi;
        }
      }
    }
  }
}

// ---------------- persistent encoder layer (zone-local barriers; R10-exact) ----------------
__global__ __launch_bounds__(256) void enc_layer(
    const float* __restrict__ GIf, const float* __restrict__ GIbk,
    const float* __restrict__ Whh, const float* __restrict__ bhh,
    const int* __restrict__ amask,
    float* __restrict__ hFa, float* __restrict__ hFb,
    float* __restrict__ hBa, float* __restrict__ hBb,
    float* __restrict__ Xout, uint* __restrict__ barbase)
{
  int dir  = blockIdx.x >> 7;
  int rr   = blockIdx.x & 127;
  int bg   = rr >> 4;
  int jblk = rr & 15;
  uint* z   = barbase + (size_t)(dir*8 + bg)*512;
  uint* ctr = z; uint* gen = z + 1;
  const float* GI = dir ? GIbk : GIf;
  const float* W  = Whh + (size_t)dir*1536*512;
  const float* bh = bhh + dir*1536;
  float* hA = dir ? hBa : hFa;
  float* hB = dir ? hBb : hFb;
  int tid = threadIdx.x;
  int bl = tid & 3, jl = (tid >> 2) & 31, kh = tid >> 7;
  int j = jblk*32 + jl;
  int b = bg*4 + bl;
  const float* w0 = W + (size_t)j*512        + kh*256;
  const float* w1 = W + (size_t)(j+512)*512  + kh*256;
  const float* w2 = W + (size_t)(j+1024)*512 + kh*256;
  float b0 = bh[j], b1 = bh[j+512], b2 = bh[j+1024];
  __shared__ float hS[4][512];   // this b-group's h, b-major: 8 KB
  __shared__ float red[256*3];
  uint e = 1;
  for (int step = 0; step < S_; step++){
    const float* hin = (step & 1) ? hB : hA;
    float*       hout= (step & 1) ? hA : hB;
    int t = dir ? (S_-1 - step) : step;
    for (int i = tid; i < 2048; i += 256){
      int bs = i >> 9, k = i & 511;
      hS[bs][k] = aload(hin + (size_t)(bg*4 + bs)*512 + k);
    }
    __syncthreads();
    float s0=0.f, s1=0.f, s2=0.f;
    #pragma unroll 8
    for (int k=0;k<256;k+=4){
      float x0 = hS[bl][kh*256 + k];
      float x1 = hS[bl][kh*256 + k + 1];
      float x2 = hS[bl][kh*256 + k + 2];
      float x3 = hS[bl][kh*256 + k + 3];
      float4 v0 = *(const float4*)(w0+k);
      float4 v1 = *(const float4*)(w1+k);
      float4 v2 = *(const float4*)(w2+k);
      s0 += x0*v0.x + x1*v0.y + x2*v0.z + x3*v0.w;
      s1 += x0*v1.x + x1*v1.y + x2*v1.z + x3*v1.w;
      s2 += x0*v2.x + x1*v2.y + x2*v2.z + x3*v2.w;
    }
    red[tid*3+0]=s0; red[tid*3+1]=s1; red[tid*3+2]=s2;
    __syncthreads();
    if (kh == 0){
      float sr = s0 + red[(tid+128)*3+0];
      float sz = s1 + red[(tid+128)*3+1];
      float sn = s2 + red[(tid+128)*3+2];
      const float* gi = GI + ((size_t)t*32 + b)*1536;
      float r = sigmoidf_(gi[j]      + sr + b0);
      float z_ = sigmoidf_(gi[j+512]  + sz + b1);
      float n = fast_tanh(gi[j+1024] + r*(sn + b2));
      float hold = hS[bl][j];
      float hn = (1.f - z_)*n + z_*hold;
      int m = amask[b*S_ + t];
      astore(hout + (size_t)b*512 + j, m ? hn : hold);
      Xout[((size_t)t*32 + b)*1024 + dir*512 + j] = m ? hn : 0.f;
    }
    gbar(ctr, gen, 16, e); e++;
  }
}

// fc init: reads B-MAJOR encoder finals, writes K-MAJOR decoder h slot-0
__global__ __launch_bounds__(256) void fc_init(
    const float* __restrict__ hF, const float* __restrict__ hB,
    const float* __restrict__ fcW, const float* __restrict__ fcb,
    float* __restrict__ h0T, float* __restrict__ h1T)
{
  int idx = blockIdx.x*256 + threadIdx.x;  // 0..32767
  int l = idx >> 14;
  int b = (idx >> 9) & 31;
  int jj = idx & 511;
  const float* w = fcW + ((size_t)(l*512 + jj))*1024;
  const float* hf = hF + (size_t)b*512;
  const float* hb = hB + (size_t)b*512;
  float s = fcb[l*512 + jj];
  #pragma unroll 4
  for (int k=0;k<512;k+=4){
    float4 wv = *(const float4*)(w+k);
    s += hf[k+0]*wv.x + hf[k+1]*wv.y + hf[k+2]*wv.z + hf[k+3]*wv.w;
    float4 wv2 = *(const float4*)(w+512+k);
    s += hb[k+0]*wv2.x + hb[k+1]*wv2.y + hb[k+2]*wv2.z + hb[k+3]*wv2.w;
  }
  __hip_atomic_store(&(l ? h1T : h0T)[jj*32 + b], fast_tanh(s),
                     __ATOMIC_RELAXED, __HIP_MEMORY_SCOPE_SYSTEM);
}

// ---------------- persistent decoder loop (R12-exact) ----------------
__global__ __launch_bounds__(256) void dec_loop(
    const float* __restrict__ ENC,  const float* __restrict__ Eenc,
    const float* __restrict__ aW,   const float* __restrict__ av,
    const int* __restrict__ amask,
    const float* __restrict__ GI0,  const float* __restrict__ Wih0,
    const float* __restrict__ Wihr, const float* __restrict__ Whh,
    const float* __restrict__ bih,  const float* __restrict__ bhh,
    float* __restrict__ h0R, float* __restrict__ h1R,
    float* __restrict__ wgtR, float* __restrict__ partR,
    float* __restrict__ Feat, uint* __restrict__ barbase)
{
  uint* ctr = barbase;            // isolated line
  uint* mir = barbase + 64;       // 8 mirrors, 128B apart
  __shared__ float eeS[128*64];    // Eenc slice, 32 KB
  __shared__ float encS[128*128];  // ENC slice, 64 KB
  __shared__ float sm[1600];
  int tid = threadIdx.x;
  int bid = blockIdx.x;
  int myMir = bid & 7;
  const float* Whh1 = Whh + (size_t)1536*512;
  const float* bih1 = bih + 1536;
  const float* bhh1 = bhh + 1536;
  uint ef = 1;
  uint ez = 1;

  int bP = bid >> 3, kg = bid & 7;
  uint* zctr = barbase + 1024 + bP*32;
  uint* zgen = zctr + 1;
  int wv = tid >> 6, ln = tid & 63;
  int jl2 = tid & 127, kh2 = tid >> 7;
  int jcol = kg*128 + jl2;

  for (int i = tid; i < 128*64; i += 256){
    int s = i >> 6, kk = i & 63;
    eeS[i] = Eenc[((size_t)s*32 + bP)*512 + kg*64 + kk];
  }
  for (int i = tid; i < 128*128; i += 256){
    int s = i >> 7, j2 = i & 127;
    encS[i] = ENC[((size_t)s*32 + bP)*1024 + kg*128 + j2];
  }
  __syncthreads();

  for (int t = 0; t < TL_; t++){
    const float* h0cur = h0R + (size_t)t*16384;
    float*       h0nxt = h0R + (size_t)(t+1)*16384;
    const float* h1cur = h1R + (size_t)t*16384;
    float*       h1nxt = h1R + (size_t)(t+1)*16384;
    float*       wgtT  = wgtR + (size_t)t*32768;
    float*       part  = partR + (size_t)t*32768;

    // ---- P1
    {
      float hreg[8];
      #pragma unroll
      for (int q=0;q<8;q++) hreg[q] = h1cur[(ln*8+q)*32 + bP];
      float avreg = av[kg*64 + ln];
      float* pre_s = sm;  // [64]
      #pragma unroll 4
      for (int i=0;i<16;i++){
        int k = kg*64 + wv*16 + i;
        const float* wr = aW + (size_t)k*1536 + ln*8;
        float4 u0 = *(const float4*)wr;
        float4 u1 = *(const float4*)(wr+4);
        float p = u0.x*hreg[0]+u0.y*hreg[1]+u0.z*hreg[2]+u0.w*hreg[3]
                + u1.x*hreg[4]+u1.y*hreg[5]+u1.z*hreg[6]+u1.w*hreg[7];
        #pragma unroll
        for (int off=32; off>0; off>>=1) p += __shfl_xor(p, off);
        if (ln == i) pre_s[wv*16+i] = p;
      }
      __syncthreads();
      float myPre = pre_s[ln];
      for (int si=0; si<32; si++){
        int s = wv*32 + si;
        float ee = eeS[s*64 + ln];
        float v = fast_tanh(myPre + ee) * avreg;
        #pragma unroll
        for (int off=32; off>0; off>>=1) v += __shfl_xor(v, off);
        if (ln == 0) astore(&part[(bP*8+kg)*128 + s], v);
      }
    }
    gbar(zctr, zgen, 8, ez); ez++;

    // ---- P2
    {
      float* praw = sm;         // [1024]
      float* sa   = sm + 1024;  // [128]
      float* aw   = sm + 1152;  // [128]
      float* red2 = sm + 1280;  // [256]
      float* sv   = sm + 1536;  // [1]
      #pragma unroll
      for (int q=0;q<4;q++) praw[tid*4+q] = part[bP*1024 + tid*4+q];
      __syncthreads();
      if (tid < 128){
        float s8 = 0.f;
        #pragma unroll
        for (int kg2=0;kg2<8;kg2++) s8 += praw[kg2*128 + tid];
        sa[tid] = amask[bP*S_ + tid] ? s8 : -1e10f;
      }
      __syncthreads();
      if (tid < 64){
        float m0 = fmaxf(sa[tid], sa[tid+64]);
        #pragma unroll
        for (int off=32; off>0; off>>=1) m0 = fmaxf(m0, __shfl_xor(m0, off));
        float e0 = __expf(sa[tid]-m0), e1 = __expf(sa[tid+64]-m0);
        aw[tid] = e0; aw[tid+64] = e1;
        float ss = e0 + e1;
        #pragma unroll
        for (int off=32; off>0; off>>=1) ss += __shfl_xor(ss, off);
        if (tid == 0) sv[0] = ss;
      }
      __syncthreads();
      float inv = 1.f / sv[0];
      float p = 0.f;
      #pragma unroll
      for (int s=0;s<64;s++) p += aw[kh2*64+s] * encS[(kh2*64+s)*128 + jl2];
      red2[jl2*2+kh2] = p;
      __syncthreads();
      if (kh2 == 0){
        float wvv = (red2[jl2*2] + red2[jl2*2+1]) * inv;
        astore(&wgtT[jcol*32 + bP], wvv);
        Feat[((size_t)t*32 + bP)*2560 + 512 + jcol] = wvv;
      }
    }
    gbarM(ctr, mir, 256, ef, myMir); ef++;

    // ---- P3
    {
      int b = tid & 31, kq = (tid >> 5) & 3, jl = tid >> 7;
      int jj = bid*2 + jl;
      const float* u0 = Wih0 + (size_t)jj*2048        + 1024 + kq*256;
      const float* u1 = Wih0 + (size_t)(jj+512)*2048  + 1024 + kq*256;
      const float* u2 = Wih0 + (size_t)(jj+1024)*2048 + 1024 + kq*256;
      const float* xT = wgtT + (size_t)(kq*256)*32 + b;
      float a0=0.f, a1=0.f, a2=0.f;
      #pragma unroll 8
      for (int k=0;k<256;k+=4){
        float x0=xT[(k+0)*32], x1=xT[(k+1)*32];
        float x2=xT[(k+2)*32], x3=xT[(k+3)*32];
        float4 v0=*(const float4*)(u0+k);
        float4 v1=*(const float4*)(u1+k);
        float4 v2=*(const float4*)(u2+k);
        a0 += x0*v0.x + x1*v0.y + x2*v0.z + x3*v0.w;
        a1 += x0*v1.x + x1*v1.y + x2*v1.z + x3*v1.w;
        a2 += x0*v2.x + x1*v2.y + x2*v2.z + x3*v2.w;
      }
      const float* w0 = Whh + (size_t)jj*512        + kq*128;
      const float* w1 = Whh + (size_t)(jj+512)*512  + kq*128;
      const float* w2 = Whh + (size_t)(jj+1024)*512 + kq*128;
      const float* hT = h0cur + (size_t)(kq*128)*32 + b;
      float s0=0.f, s1=0.f, s2=0.f;
      #pragma unroll 8
      for (int k=0;k<128;k+=4){
        float x0=hT[(k+0)*32], x1=hT[(k+1)*32];
        float x2=hT[(k+2)*32], x3=hT[(k+3)*32];
        float4 v0=*(const float4*)(w0+k);
        float4 v1=*(const float4*)(w1+k);
        float4 v2=*(const float4*)(w2+k);
        s0 += x0*v0.x + x1*v0.y + x2*v0.z + x3*v0.w;
        s1 += x0*v1.x + x1*v1.y + x2*v1.z + x3*v1.w;
        s2 += x0*v2.x + x1*v2.y + x2*v2.z + x3*v2.w;
      }
      float* red = sm;
      int ridx = ((jl*4 + kq)*32 + b)*4;
      red[ridx+0] = a0 + s0;
      red[ridx+1] = a1 + s1;
      red[ridx+2] = a2;
      red[ridx+3] = s2;
      __syncthreads();
      if (kq == 0){
        float P0=0.f, P1=0.f, P2=0.f, P3=0.f;
        #pragma unroll
        for (int q=0;q<4;q++){
          int ri = ((jl*4 + q)*32 + b)*4;
          P0 += red[ri+0]; P1 += red[ri+1]; P2 += red[ri+2]; P3 += red[ri+3];
        }
        const float* gi = GI0 + ((size_t)t*32 + b)*1536;
        float r = sigmoidf_(gi[jj]      + P0 + bhh[jj]);
        float z_ = sigmoidf_(gi[jj+512]  + P1 + bhh[jj+512]);
        float n = fast_tanh(gi[jj+1024] + P2 + r*(P3 + bhh[jj+1024]));
        float hold = h0cur[jj*32 + b];
        astore(h0nxt + jj*32 + b, (1.f - z_)*n + z_*hold);
      }
    }
    gbarM(ctr, mir, 256, ef, myMir); ef++;

    // ---- P4
    {
      int b = tid & 31, kq = (tid >> 5) & 3, jl = tid >> 7;
      int jj = bid*2 + jl;
      const float* i0 = Wihr + (size_t)jj*512        + kq*128;
      const float* i1 = Wihr + (size_t)(jj+512)*512  + kq*128;
      const float* i2 = Wihr + (size_t)(jj+1024)*512 + kq*128;
      const float* xT = h0nxt + (size_t)(kq*128)*32 + b;
      float a0=0.f, a1=0.f, a2=0.f;
      #pragma unroll 8
      for (int k=0;k<128;k+=4){
        float x0=xT[(k+0)*32], x1=xT[(k+1)*32];
        float x2=xT[(k+2)*32], x3=xT[(k+3)*32];
        float4 v0=*(const float4*)(i0+k);
        float4 v1=*(const float4*)(i1+k);
        float4 v2=*(const float4*)(i2+k);
        a0 += x0*v0.x + x1*v0.y + x2*v0.z + x3*v0.w;
        a1 += x0*v1.x + x1*v1.y + x2*v1.z + x3*v1.w;
        a2 += x0*v2.x + x1*v2.y + x2*v2.z + x3*v2.w;
      }
      const float* w0 = Whh1 + (size_t)jj*512        + kq*128;
      const float* w1 = Whh1 + (size_t)(jj+512)*512  + kq*128;
      const float* w2 = Whh1 + (size_t)(jj+1024)*512 + kq*128;
      const float* hT = h1cur + (size_t)(kq*128)*32 + b;
      float s0=0.f, s1=0.f, s2=0.f;
      #pragma unroll 8
      for (int k=0;k<128;k+=4){
        float x0=hT[(k+0)*32], x1=hT[(k+1)*32];
        float x2=hT[(k+2)*32], x3=hT[(k+3)*32];
        float4 v0=*(const float4*)(w0+k);
        float4 v1=*(const float4*)(w1+k);
        float4 v2=*(const float4*)(w2+k);
        s0 += x0*v0.x + x1*v0.y + x2*v0.z + x3*v0.w;
        s1 += x0*v1.x + x1*v1.y + x2*v1.z + x3*v1.w;
        s2 += x0*v2.x + x1*v2.y + x2*v2.z + x3*v2.w;
      }
      float* red = sm;
      int ridx = ((jl*4 + kq)*32 + b)*4;
      red[ridx+0] = a0 + s0;
      red[ridx+1] = a1 + s1;
      red[ridx+2] = a2;
      red[ridx+3] = s2;
      __syncthreads();
      if (kq == 0){
        float P0=0.f, P1=0.f, P2=0.f, P3=0.f;
        #pragma unroll
        for (int q=0;q<4;q++){
          int ri = ((jl*4 + q)*32 + b)*4;
          P0 += red[ri+0]; P1 += red[ri+1]; P2 += red[ri+2]; P3 += red[ri+3];
        }
        float r = sigmoidf_(P0 + bih1[jj]      + bhh1[jj]);
        float z_ = sigmoidf_(P1 + bih1[jj+512]  + bhh1[jj+512]);
        float n = fast_tanh(P2 + bih1[jj+1024] + r*(P3 + bhh1[jj+1024]));
        float hold = h1cur[jj*32 + b];
        float hn = (1.f - z_)*n + z_*hold;
        astore(h1nxt + jj*32 + b, hn);
        Feat[((size_t)t*32 + b)*2560 + jj] = hn;
      }
    }
    gbarM(ctr, mir, 256, ef, myMir); ef++;
  }
}

// zero the t=0 plane of out
__global__ __launch_bounds__(256) void zero_t0(float* __restrict__ out){
  int idx = blockIdx.x*256 + threadIdx.x;
  if (idx < 32*V){
    int b = idx / V, v = idx - b*V;
    out[(size_t)b*64*V + v] = 0.f;
  }
}

// ---------------- bf16 MFMA output GEMM (R13-exact) ----------------
__global__ __launch_bounds__(256) void out_gemm(
    const float* __restrict__ A,    // Feat [2016][2560]
    const float* __restrict__ Bw,   // out_W [32000][2560]
    const float* __restrict__ bias, // out_b [32000]
    float* __restrict__ out)        // [32][64][32000]
{
  __shared__ ushort As[4][129][8];
  __shared__ ushort Bs[4][129][8];
  int tid = threadIdx.x;
  int lane = tid & 63, wid = tid >> 6;
  // bijective XCD swizzle: 4000 % 8 == 0
  int orig = ((int)blockIdx.x & 7)*500 + ((int)blockIdx.x >> 3);
  int row0 = (orig & 15)*128, col0 = (orig >> 4)*128;
  int sr = tid >> 1;
  int s0 = (tid & 1) * 2;
  int sk = (tid & 1) * 16;
  int arow = row0 + sr; if (arow > 2015) arow = 2015;
  const float* Ap = A + (size_t)arow*2560 + sk;
  const float* Bp = Bw + (size_t)(col0 + sr)*2560 + sk;
  int wr = (wid >> 1)*64, wc = (wid & 1)*64;
  int fr = lane & 15, slot = lane >> 4;
  f32x4 acc[4][4];
  #pragma unroll
  for (int m=0;m<4;m++){
    #pragma unroll
    for (int n=0;n<4;n++) acc[m][n] = (f32x4){0.f,0.f,0.f,0.f};
  }
  for (int k0 = 0; k0 < 2560; k0 += 32){
    float4 a0 = *(const float4*)(Ap + k0);
    float4 a1 = *(const float4*)(Ap + k0 + 4);
    float4 a2 = *(const float4*)(Ap + k0 + 8);
    float4 a3 = *(const float4*)(Ap + k0 + 12);
    float4 b0 = *(const float4*)(Bp + k0);
    float4 b1 = *(const float4*)(Bp + k0 + 4);
    float4 b2 = *(const float4*)(Bp + k0 + 8);
    float4 b3 = *(const float4*)(Bp + k0 + 12);
    __syncthreads();
    uint4 ua, ua2, ub, ub2;
    ua.x  = cvtpk(a0.x, a0.y); ua.y  = cvtpk(a0.z, a0.w);
    ua.z  = cvtpk(a1.x, a1.y); ua.w  = cvtpk(a1.z, a1.w);
    ua2.x = cvtpk(a2.x, a2.y); ua2.y = cvtpk(a2.z, a2.w);
    ua2.z = cvtpk(a3.x, a3.y); ua2.w = cvtpk(a3.z, a3.w);
    ub.x  = cvtpk(b0.x, b0.y); ub.y  = cvtpk(b0.z, b0.w);
    ub.z  = cvtpk(b1.x, b1.y); ub.w  = cvtpk(b1.z, b1.w);
    ub2.x = cvtpk(b2.x, b2.y); ub2.y = cvtpk(b2.z, b2.w);
    ub2.z = cvtpk(b3.x, b3.y); ub2.w = cvtpk(b3.z, b3.w);
    *(uint4*)&As[s0  ][sr][0] = ua;
    *(uint4*)&As[s0+1][sr][0] = ua2;
    *(uint4*)&Bs[s0  ][sr][0] = ub;
    *(uint4*)&Bs[s0+1][sr][0] = ub2;
    __syncthreads();
    short8 af[4], bfr[4];
    #pragma unroll
    for (int m=0;m<4;m++) af[m]  = *(const short8*)&As[slot][wr + m*16 + fr][0];
    #pragma unroll
    for (int n=0;n<4;n++) bfr[n] = *(const short8*)&Bs[slot][wc + n*16 + fr][0];
    #pragma unroll
    for (int m=0;m<4;m++){
      #pragma unroll
      for (int n=0;n<4;n++)
        acc[m][n] = __builtin_amdgcn_mfma_f32_16x16x32_bf16(af[m], bfr[n], acc[m][n], 0, 0, 0);
    }
  }
  int cb = lane & 15, rb = (lane >> 4)*4;
  #pragma unroll
  for (int m=0;m<4;m++){
    #pragma unroll
    for (int n=0;n<4;n++){
      int c = col0 + wc + n*16 + cb;
      float bi = bias[c];
      #pragma unroll
      for (int j=0;j<4;j++){
        int r = row0 + wr + m*16 + rb + j;
        if (r < 2016){
          int bb = r & 31, tt = r >> 5;
          out[((size_t)bb*64 + tt + 1)*V + c] = acc[m][n][j] + bi;
        }
      }
    }
  }
}

extern "C" void kernel_launch(void* const* d_in, const int* in_sizes, int n_in,
                              void* d_out, int out_size, void* d_ws, size_t ws_size,
                              hipStream_t stream) {
  (void)in_sizes; (void)n_in; (void)out_size; (void)ws_size;
  const int*   ids    = (const int*)d_in[0];
  const int*   amask  = (const int*)d_in[1];
  const int*   labels = (const int*)d_in[2];
  const float* enc_emb= (const float*)d_in[3];
  const float* eWih   = (const float*)d_in[4];
  const float* eWhh   = (const float*)d_in[5];
  const float* ebih   = (const float*)d_in[6];
  const float* ebhh   = (const float*)d_in[7];
  const float* fcW    = (const float*)d_in[8];
  const float* fcb    = (const float*)d_in[9];
  const float* aW     = (const float*)d_in[10];
  const float* ab     = (const float*)d_in[11];
  const float* av     = (const float*)d_in[12];
  const float* dec_emb= (const float*)d_in[13];
  const float* dWih0  = (const float*)d_in[14];
  const float* dWihr  = (const float*)d_in[15];
  const float* dWhh   = (const float*)d_in[16];
  const float* dbih   = (const float*)d_in[17];
  const float* dbhh   = (const float*)d_in[18];
  const float* outW   = (const float*)d_in[19];
  const float* outb   = (const float*)d_in[20];
  float* out = (float*)d_out;

  // barrier zones: enc layer l zone (dir,bg) at bar + l*8192 + (dir*8+bg)*512
  // (16384 uints); dec at bar + 16384: ctr@0, mirrors@64..288, bP zones@1024+.
  uint*  bar = (uint*)d_ws;
  float* ws  = (float*)d_ws + 20480;
  float* X0  = ws;
  float* X1  = X0  + (size_t)4096*1024;
  float* ENC = X1  + (size_t)4096*1024;
  float* GIa = ENC + (size_t)4096*1024;
  float* GIb = GIa + (size_t)4096*1536;
  float* Eenc= GIb + (size_t)4096*1536;
  float* GI0 = Eenc+ (size_t)4096*512;
  float* Feat= GI0 + (size_t)2016*1536;
  float* hp  = Feat+ (size_t)2016*2560;
  float* hFa = hp;             float* hFb = hFa + 32*512;
  float* hBa = hFb + 32*512;   float* hBb = hBa + 32*512;
  // rotating decoder buffers live in the X0/X1 regions (dead by decoder time)
  float* wgtR  = X0;                          // 63 * 32768
  float* partR = X0 + (size_t)63*32768;       // 63 * 32768
  float* h0R   = X1;                          // 64 * 16384
  float* h1R   = X1 + (size_t)64*16384;       // 64 * 16384

  hipMemsetAsync(bar, 0, 20480*sizeof(uint), stream);

  // ---- encoder ----
  embed_enc<<<4096, 256, 0, stream>>>(ids, enc_emb, X0);
  for (int l = 0; l < NL; l++){
    const float* Xin = l ? X1 : X0;
    float* Xout = l ? ENC : X1;
    hipMemsetAsync(hFa, 0, 32*512*sizeof(float), stream);
    hipMemsetAsync(hBa, 0, 32*512*sizeof(float), stream);
    gemm_bf16<<<dim3(32,12),256,0,stream>>>(Xin, 1024, eWih + (size_t)(l*2+0)*1536*1024, 1024,
        ebih + (l*2+0)*1536, GIa, 1536, 4096, 1536, 1024);
    gemm_bf16<<<dim3(32,12),256,0,stream>>>(Xin, 1024, eWih + (size_t)(l*2+1)*1536*1024, 1024,
        ebih + (l*2+1)*1536, GIb, 1536, 4096, 1536, 1024);
    {
      const float* gia = GIa; const float* gib = GIb;
      const float* whhp = eWhh + (size_t)l*2*1536*512;
      const float* bhhp = ebhh + (size_t)l*2*1536;
      uint* eb = bar + (size_t)l*8192;
      void* args[] = {(void*)&gia, (void*)&gib, (void*)&whhp, (void*)&bhhp,
                      (void*)&amask, (void*)&hFa, (void*)&hFb, (void*)&hBa,
                      (void*)&hBb, (void*)&Xout, (void*)&eb};
      hipLaunchCooperativeKernel((const void*)enc_layer, dim3(256), dim3(256), args, 0, stream);
    }
  }
  // ---- decoder setup ----
  fc_init<<<128,256,0,stream>>>(hFa, hBa, fcW, fcb, h0R, h1R);
  gemm_bf16<<<dim3(32,4),256,0,stream>>>(ENC, 1024, aW + 512, 1536, ab, Eenc, 512, 4096, 512, 1024);
  embed_dec<<<2016,256,0,stream>>>(labels, dec_emb, Feat);
  gemm_bf16<<<dim3(16,12),256,0,stream>>>(Feat + 1536, 2560, dWih0, 2048, dbih, GI0, 1536, 2016, 1536, 1024);
  // ---- decoder loop ----
  {
    const float* encp = ENC; const float* eencp = Eenc; const float* gi0p = GI0;
    float* featp = Feat;
    uint* db = bar + 16384;
    void* args[] = {(void*)&encp, (void*)&eencp, (void*)&aW, (void*)&av,
                    (void*)&amask, (void*)&gi0p, (void*)&dWih0, (void*)&dWihr,
                    (void*)&dWhh, (void*)&dbih, (void*)&dbhh,
                    (void*)&h0R, (void*)&h1R, (void*)&wgtR, (void*)&partR,
                    (void*)&featp, (void*)&db};
    hipLaunchCooperativeKernel((const void*)dec_loop, dim3(256), dim3(256), args, 0, stream);
  }
  // ---- output ----
  zero_t0<<<4000,256,0,stream>>>(out);
  out_gemm<<<4000,256,0,stream>>>(Feat, outW, outb, out);
}

// Round 15
// 9041.238 us; speedup vs baseline: 1.1104x; 1.0120x over previous
//
#include <hip/hip_runtime.h>
#include <hip/hip_bf16.h>

// Sizes (compile-time)
#define V 32000
#define E 1024
#define H 512
#define NL 2
#define B_ 32
#define S_ 128
#define TL_ 63

typedef __attribute__((ext_vector_type(8))) short short8;
typedef __attribute__((ext_vector_type(4))) float f32x4;

__device__ __forceinline__ float sigmoidf_(float x){ return 1.f/(1.f + __expf(-x)); }
__device__ __forceinline__ float fast_tanh(float x){ return 1.f - 2.f/(__expf(2.f*x) + 1.f); }
// packed f32x2 -> bf16x2 (RNE), 1 VALU op (gfx950)
__device__ __forceinline__ uint cvtpk(float lo, float hi){
  uint r;
  asm("v_cvt_pk_bf16_f32 %0, %1, %2" : "=v"(r) : "v"(lo), "v"(hi));
  return r;
}

// SYSTEM-scope (bypass L1+L2, ack at MALL) accessors for cross-block state.
__device__ __forceinline__ float aload(const float* p){
  return __hip_atomic_load(p, __ATOMIC_RELAXED, __HIP_MEMORY_SCOPE_SYSTEM);
}
__device__ __forceinline__ void astore(float* p, float v){
  __hip_atomic_store(p, v, __ATOMIC_RELAXED, __HIP_MEMORY_SCOPE_SYSTEM);
}

// fenceless grid barrier (R7-proven, flat): used for small zones (8-16 pollers).
__device__ __forceinline__ void gbar(uint* ctr, uint* gen, uint nblk, uint e){
  __syncthreads();
  if (threadIdx.x == 0){
    uint old = __hip_atomic_fetch_add(ctr, 1u, __ATOMIC_RELAXED, __HIP_MEMORY_SCOPE_SYSTEM);
    if (old == e*nblk - 1u){
      __hip_atomic_store(gen, e, __ATOMIC_RELAXED, __HIP_MEMORY_SCOPE_SYSTEM);
    } else {
      while (__hip_atomic_load(gen, __ATOMIC_RELAXED, __HIP_MEMORY_SCOPE_SYSTEM) < e)
        __builtin_amdgcn_s_sleep(2);
    }
  }
  __syncthreads();
}

// Hierarchical mirrored full-grid barrier (R12 mirrors + 2-level arrival).
// With the poll storm fixed (R12: -4.6us/barrier), the remaining ~20us/barrier
// is modeled as 256 serialized arrival RMWs on one MALL line. Split arrival:
// 32 group-ctrs (8 blocks each, distinct 128B lines -> RMWs parallel across
// lines), group-last does 1 of 32 global RMWs, global-last fans out to the 8
// gen mirrors. Ordering chain data->groupRMW->globalRMW->mirror is preserved
// by RMW completion; the release leader's poll is trivially satisfied.
__device__ __forceinline__ void gbarH(uint* ctr, uint* mir, uint* gctr, uint e, int myMir){
  __syncthreads();
  if (threadIdx.x == 0){
    uint g = __hip_atomic_fetch_add(gctr, 1u, __ATOMIC_RELAXED, __HIP_MEMORY_SCOPE_SYSTEM);
    if (g == e*8u - 1u){
      uint o = __hip_atomic_fetch_add(ctr, 1u, __ATOMIC_RELAXED, __HIP_MEMORY_SCOPE_SYSTEM);
      if (o == e*32u - 1u){
        #pragma unroll
        for (int m = 0; m < 8; m++)
          __hip_atomic_store(&mir[m*32], e, __ATOMIC_RELAXED, __HIP_MEMORY_SCOPE_SYSTEM);
      }
    }
    while (__hip_atomic_load(&mir[myMir*32], __ATOMIC_RELAXED, __HIP_MEMORY_SCOPE_SYSTEM) < e)
      __builtin_amdgcn_s_sleep(32);
  }
  __syncthreads();
}

// ---------------- embedding gathers ----------------
__global__ __launch_bounds__(256) void embed_enc(const int* __restrict__ ids,
                                                 const float* __restrict__ emb,
                                                 float* __restrict__ X0){
  int row = blockIdx.x;              // 0..4095 = s*32+b
  int s = row >> 5, b = row & 31;
  int tok = ids[b*S_ + s];
  const float4* src = (const float4*)(emb + (size_t)tok*E);
  float4* dst = (float4*)(X0 + (size_t)row*E);
  dst[threadIdx.x] = src[threadIdx.x];
}

__global__ __launch_bounds__(256) void embed_dec(const int* __restrict__ labels,
                                                 const float* __restrict__ emb,
                                                 float* __restrict__ Feat){
  int row = blockIdx.x;              // 0..2015 = t*32+b
  int t = row >> 5, b = row & 31;
  int tok = (t == 0) ? 1 : labels[b*TL_ + (t-1)];
  if (tok == -100) tok = 0;
  const float4* src = (const float4*)(emb + (size_t)tok*E);
  float4* dst = (float4*)(Feat + (size_t)row*2560 + 1536);
  dst[threadIdx.x] = src[threadIdx.x];
}

// ---------------- bf16 MFMA GEMM: C[M][N] = A[M][K] @ B[N][K]^T + bias[N] ----------------
__global__ __launch_bounds__(256) void gemm_bf16(
    const float* __restrict__ A, int lda,
    const float* __restrict__ B, int ldb,
    const float* __restrict__ bias,
    float* __restrict__ C, int ldc,
    int M, int N, int K)
{
  __shared__ ushort As[4][129][8];
  __shared__ ushort Bs[4][129][8];
  int tid = threadIdx.x;
  int lane = tid & 63, wid = tid >> 6;
  int row0 = blockIdx.x*128, col0 = blockIdx.y*128;
  int sr = tid >> 1;
  int s0 = (tid & 1) * 2;
  int sk = (tid & 1) * 16;
  int arow = row0 + sr; if (arow > M-1) arow = M-1;
  const float* Ap = A + (size_t)arow*lda + sk;
  const float* Bp = B + (size_t)(col0 + sr)*ldb + sk;
  int wr = (wid >> 1)*64, wc = (wid & 1)*64;
  int fr = lane & 15, slot = lane >> 4;
  f32x4 acc[4][4];
  #pragma unroll
  for (int m=0;m<4;m++){
    #pragma unroll
    for (int n=0;n<4;n++) acc[m][n] = (f32x4){0.f,0.f,0.f,0.f};
  }
  for (int k0 = 0; k0 < K; k0 += 32){
    float4 a0 = *(const float4*)(Ap + k0);
    float4 a1 = *(const float4*)(Ap + k0 + 4);
    float4 a2 = *(const float4*)(Ap + k0 + 8);
    float4 a3 = *(const float4*)(Ap + k0 + 12);
    float4 b0 = *(const float4*)(Bp + k0);
    float4 b1 = *(const float4*)(Bp + k0 + 4);
    float4 b2 = *(const float4*)(Bp + k0 + 8);
    float4 b3 = *(const float4*)(Bp + k0 + 12);
    __syncthreads();
    uint4 ua, ua2, ub, ub2;
    ua.x  = cvtpk(a0.x, a0.y); ua.y  = cvtpk(a0.z, a0.w);
    ua.z  = cvtpk(a1.x, a1.y); ua.w  = cvtpk(a1.z, a1.w);
    ua2.x = cvtpk(a2.x, a2.y); ua2.y = cvtpk(a2.z, a2.w);
    ua2.z = cvtpk(a3.x, a3.y); ua2.w = cvtpk(a3.z, a3.w);
    ub.x  = cvtpk(b0.x, b0.y); ub.y  = cvtpk(b0.z, b0.w);
    ub.z  = cvtpk(b1.x, b1.y); ub.w  = cvtpk(b1.z, b1.w);
    ub2.x = cvtpk(b2.x, b2.y); ub2.y = cvtpk(b2.z, b2.w);
    ub2.z = cvtpk(b3.x, b3.y); ub2.w = cvtpk(b3.z, b3.w);
    *(uint4*)&As[s0  ][sr][0] = ua;
    *(uint4*)&As[s0+1][sr][0] = ua2;
    *(uint4*)&Bs[s0  ][sr][0] = ub;
    *(uint4*)&Bs[s0+1][sr][0] = ub2;
    __syncthreads();
    short8 af[4], bfr[4];
    #pragma unroll
    for (int m=0;m<4;m++) af[m]  = *(const short8*)&As[slot][wr + m*16 + fr][0];
    #pragma unroll
    for (int n=0;n<4;n++) bfr[n] = *(const short8*)&Bs[slot][wc + n*16 + fr][0];
    #pragma unroll
    for (int m=0;m<4;m++){
      #pragma unroll
      for (int n=0;n<4;n++)
        acc[m][n] = __builtin_amdgcn_mfma_f32_16x16x32_bf16(af[m], bfr[n], acc[m][n], 0, 0, 0);
    }
  }
  int cb = lane & 15, rb = (lane >> 4)*4;
  #pragma unroll
  for (int m=0;m<4;m++){
    #pragma unroll
    for (int n=0;n<4;n++){
      int c = col0 + wc + n*16 + cb;
      float bi = bias[c];
      #pragma unroll
      for (int j=0;j<4;j++){
        int r = row0 + wr + m*16 + rb + j;
        if (r < M){
          C[(size_t)r*ldc + c] = acc[m][n][j] + bi;
        }
      }
    }
  }
}

// ---------------- persistent encoder layer (zone-local barriers; R10-exact) ----------------
__global__ __launch_bounds__(256) void enc_layer(
    const float* __restrict__ GIf, const float* __restrict__ GIbk,
    const float* __restrict__ Whh, const float* __restrict__ bhh,
    const int* __restrict__ amask,
    float* __restrict__ hFa, float* __restrict__ hFb,
    float* __restrict__ hBa, float* __restrict__ hBb,
    float* __restrict__ Xout, uint* __restrict__ barbase)
{
  int dir  = blockIdx.x >> 7;
  int rr   = blockIdx.x & 127;
  int bg   = rr >> 4;
  int jblk = rr & 15;
  uint* z   = barbase + (size_t)(dir*8 + bg)*512;
  uint* ctr = z; uint* gen = z + 1;
  const float* GI = dir ? GIbk : GIf;
  const float* W  = Whh + (size_t)dir*1536*512;
  const float* bh = bhh + dir*1536;
  float* hA = dir ? hBa : hFa;
  float* hB = dir ? hBb : hFb;
  int tid = threadIdx.x;
  int bl = tid & 3, jl = (tid >> 2) & 31, kh = tid >> 7;
  int j = jblk*32 + jl;
  int b = bg*4 + bl;
  const float* w0 = W + (size_t)j*512        + kh*256;
  const float* w1 = W + (size_t)(j+512)*512  + kh*256;
  const float* w2 = W + (size_t)(j+1024)*512 + kh*256;
  float b0 = bh[j], b1 = bh[j+512], b2 = bh[j+1024];
  __shared__ float hS[4][512];   // this b-group's h, b-major: 8 KB
  __shared__ float red[256*3];
  uint e = 1;
  for (int step = 0; step < S_; step++){
    const float* hin = (step & 1) ? hB : hA;
    float*       hout= (step & 1) ? hA : hB;
    int t = dir ? (S_-1 - step) : step;
    for (int i = tid; i < 2048; i += 256){
      int bs = i >> 9, k = i & 511;
      hS[bs][k] = aload(hin + (size_t)(bg*4 + bs)*512 + k);
    }
    __syncthreads();
    float s0=0.f, s1=0.f, s2=0.f;
    #pragma unroll 8
    for (int k=0;k<256;k+=4){
      float x0 = hS[bl][kh*256 + k];
      float x1 = hS[bl][kh*256 + k + 1];
      float x2 = hS[bl][kh*256 + k + 2];
      float x3 = hS[bl][kh*256 + k + 3];
      float4 v0 = *(const float4*)(w0+k);
      float4 v1 = *(const float4*)(w1+k);
      float4 v2 = *(const float4*)(w2+k);
      s0 += x0*v0.x + x1*v0.y + x2*v0.z + x3*v0.w;
      s1 += x0*v1.x + x1*v1.y + x2*v1.z + x3*v1.w;
      s2 += x0*v2.x + x1*v2.y + x2*v2.z + x3*v2.w;
    }
    red[tid*3+0]=s0; red[tid*3+1]=s1; red[tid*3+2]=s2;
    __syncthreads();
    if (kh == 0){
      float sr = s0 + red[(tid+128)*3+0];
      float sz = s1 + red[(tid+128)*3+1];
      float sn = s2 + red[(tid+128)*3+2];
      const float* gi = GI + ((size_t)t*32 + b)*1536;
      float r = sigmoidf_(gi[j]      + sr + b0);
      float z_ = sigmoidf_(gi[j+512]  + sz + b1);
      float n = fast_tanh(gi[j+1024] + r*(sn + b2));
      float hold = hS[bl][j];
      float hn = (1.f - z_)*n + z_*hold;
      int m = amask[b*S_ + t];
      astore(hout + (size_t)b*512 + j, m ? hn : hold);
      Xout[((size_t)t*32 + b)*1024 + dir*512 + j] = m ? hn : 0.f;
    }
    gbar(ctr, gen, 16, e); e++;
  }
}

// fc init: reads B-MAJOR encoder finals, writes K-MAJOR decoder h slot-0
__global__ __launch_bounds__(256) void fc_init(
    const float* __restrict__ hF, const float* __restrict__ hB,
    const float* __restrict__ fcW, const float* __restrict__ fcb,
    float* __restrict__ h0T, float* __restrict__ h1T)
{
  int idx = blockIdx.x*256 + threadIdx.x;  // 0..32767
  int l = idx >> 14;
  int b = (idx >> 9) & 31;
  int jj = idx & 511;
  const float* w = fcW + ((size_t)(l*512 + jj))*1024;
  const float* hf = hF + (size_t)b*512;
  const float* hb = hB + (size_t)b*512;
  float s = fcb[l*512 + jj];
  #pragma unroll 4
  for (int k=0;k<512;k+=4){
    float4 wv = *(const float4*)(w+k);
    s += hf[k+0]*wv.x + hf[k+1]*wv.y + hf[k+2]*wv.z + hf[k+3]*wv.w;
    float4 wv2 = *(const float4*)(w+512+k);
    s += hb[k+0]*wv2.x + hb[k+1]*wv2.y + hb[k+2]*wv2.z + hb[k+3]*wv2.w;
  }
  __hip_atomic_store(&(l ? h1T : h0T)[jj*32 + b], fast_tanh(s),
                     __ATOMIC_RELAXED, __HIP_MEMORY_SCOPE_SYSTEM);
}

// ---------------- persistent decoder loop (R14 data path; hierarchical barrier) ----------------
__global__ __launch_bounds__(256) void dec_loop(
    const float* __restrict__ ENC,  const float* __restrict__ Eenc,
    const float* __restrict__ aW,   const float* __restrict__ av,
    const int* __restrict__ amask,
    const float* __restrict__ GI0,  const float* __restrict__ Wih0,
    const float* __restrict__ Wihr, const float* __restrict__ Whh,
    const float* __restrict__ bih,  const float* __restrict__ bhh,
    float* __restrict__ h0R, float* __restrict__ h1R,
    float* __restrict__ wgtR, float* __restrict__ partR,
    float* __restrict__ Feat, uint* __restrict__ barbase)
{
  uint* ctr = barbase;            // isolated line
  uint* mir = barbase + 64;       // 8 mirrors, 128B apart
  __shared__ float eeS[128*64];    // Eenc slice, 32 KB
  __shared__ float encS[128*128];  // ENC slice, 64 KB
  __shared__ float sm[1600];
  int tid = threadIdx.x;
  int bid = blockIdx.x;
  int myMir = bid & 7;
  uint* gctr = barbase + 2048 + (bid >> 3)*32;  // 32 group ctrs, 128B apart
  const float* Whh1 = Whh + (size_t)1536*512;
  const float* bih1 = bih + 1536;
  const float* bhh1 = bhh + 1536;
  uint ef = 1;
  uint ez = 1;

  int bP = bid >> 3, kg = bid & 7;
  uint* zctr = barbase + 1024 + bP*32;
  uint* zgen = zctr + 1;
  int wv = tid >> 6, ln = tid & 63;
  int jl2 = tid & 127, kh2 = tid >> 7;
  int jcol = kg*128 + jl2;

  for (int i = tid; i < 128*64; i += 256){
    int s = i >> 6, kk = i & 63;
    eeS[i] = Eenc[((size_t)s*32 + bP)*512 + kg*64 + kk];
  }
  for (int i = tid; i < 128*128; i += 256){
    int s = i >> 7, j2 = i & 127;
    encS[i] = ENC[((size_t)s*32 + bP)*1024 + kg*128 + j2];
  }
  __syncthreads();

  for (int t = 0; t < TL_; t++){
    const float* h0cur = h0R + (size_t)t*16384;
    float*       h0nxt = h0R + (size_t)(t+1)*16384;
    const float* h1cur = h1R + (size_t)t*16384;
    float*       h1nxt = h1R + (size_t)(t+1)*16384;
    float*       wgtT  = wgtR + (size_t)t*32768;
    float*       part  = partR + (size_t)t*32768;

    // ---- P1
    {
      float hreg[8];
      #pragma unroll
      for (int q=0;q<8;q++) hreg[q] = h1cur[(ln*8+q)*32 + bP];
      float avreg = av[kg*64 + ln];
      float* pre_s = sm;  // [64]
      #pragma unroll 4
      for (int i=0;i<16;i++){
        int k = kg*64 + wv*16 + i;
        const float* wr = aW + (size_t)k*1536 + ln*8;
        float4 u0 = *(const float4*)wr;
        float4 u1 = *(const float4*)(wr+4);
        float p = u0.x*hreg[0]+u0.y*hreg[1]+u0.z*hreg[2]+u0.w*hreg[3]
                + u1.x*hreg[4]+u1.y*hreg[5]+u1.z*hreg[6]+u1.w*hreg[7];
        #pragma unroll
        for (int off=32; off>0; off>>=1) p += __shfl_xor(p, off);
        if (ln == i) pre_s[wv*16+i] = p;
      }
      __syncthreads();
      float myPre = pre_s[ln];
      for (int si=0; si<32; si++){
        int s = wv*32 + si;
        float ee = eeS[s*64 + ln];
        float v = fast_tanh(myPre + ee) * avreg;
        #pragma unroll
        for (int off=32; off>0; off>>=1) v += __shfl_xor(v, off);
        if (ln == 0) astore(&part[(bP*8+kg)*128 + s], v);
      }
    }
    gbar(zctr, zgen, 8, ez); ez++;

    // ---- P2
    {
      float* praw = sm;         // [1024]
      float* sa   = sm + 1024;  // [128]
      float* aw   = sm + 1152;  // [128]
      float* red2 = sm + 1280;  // [256]
      float* sv   = sm + 1536;  // [1]
      #pragma unroll
      for (int q=0;q<4;q++) praw[tid*4+q] = part[bP*1024 + tid*4+q];
      __syncthreads();
      if (tid < 128){
        float s8 = 0.f;
        #pragma unroll
        for (int kg2=0;kg2<8;kg2++) s8 += praw[kg2*128 + tid];
        sa[tid] = amask[bP*S_ + tid] ? s8 : -1e10f;
      }
      __syncthreads();
      if (tid < 64){
        float m0 = fmaxf(sa[tid], sa[tid+64]);
        #pragma unroll
        for (int off=32; off>0; off>>=1) m0 = fmaxf(m0, __shfl_xor(m0, off));
        float e0 = __expf(sa[tid]-m0), e1 = __expf(sa[tid+64]-m0);
        aw[tid] = e0; aw[tid+64] = e1;
        float ss = e0 + e1;
        #pragma unroll
        for (int off=32; off>0; off>>=1) ss += __shfl_xor(ss, off);
        if (tid == 0) sv[0] = ss;
      }
      __syncthreads();
      float inv = 1.f / sv[0];
      float p = 0.f;
      #pragma unroll
      for (int s=0;s<64;s++) p += aw[kh2*64+s] * encS[(kh2*64+s)*128 + jl2];
      red2[jl2*2+kh2] = p;
      __syncthreads();
      if (kh2 == 0){
        float wvv = (red2[jl2*2] + red2[jl2*2+1]) * inv;
        astore(&wgtT[jcol*32 + bP], wvv);
        Feat[((size_t)t*32 + bP)*2560 + 512 + jcol] = wvv;
      }
    }
    gbarH(ctr, mir, gctr, ef, myMir); ef++;

    // ---- P3
    {
      int b = tid & 31, kq = (tid >> 5) & 3, jl = tid >> 7;
      int jj = bid*2 + jl;
      const float* u0 = Wih0 + (size_t)jj*2048        + 1024 + kq*256;
      const float* u1 = Wih0 + (size_t)(jj+512)*2048  + 1024 + kq*256;
      const float* u2 = Wih0 + (size_t)(jj+1024)*2048 + 1024 + kq*256;
      const float* xT = wgtT + (size_t)(kq*256)*32 + b;
      float a0=0.f, a1=0.f, a2=0.f;
      #pragma unroll 8
      for (int k=0;k<256;k+=4){
        float x0=xT[(k+0)*32], x1=xT[(k+1)*32];
        float x2=xT[(k+2)*32], x3=xT[(k+3)*32];
        float4 v0=*(const float4*)(u0+k);
        float4 v1=*(const float4*)(u1+k);
        float4 v2=*(const float4*)(u2+k);
        a0 += x0*v0.x + x1*v0.y + x2*v0.z + x3*v0.w;
        a1 += x0*v1.x + x1*v1.y + x2*v1.z + x3*v1.w;
        a2 += x0*v2.x + x1*v2.y + x2*v2.z + x3*v2.w;
      }
      const float* w0 = Whh + (size_t)jj*512        + kq*128;
      const float* w1 = Whh + (size_t)(jj+512)*512  + kq*128;
      const float* w2 = Whh + (size_t)(jj+1024)*512 + kq*128;
      const float* hT = h0cur + (size_t)(kq*128)*32 + b;
      float s0=0.f, s1=0.f, s2=0.f;
      #pragma unroll 8
      for (int k=0;k<128;k+=4){
        float x0=hT[(k+0)*32], x1=hT[(k+1)*32];
        float x2=hT[(k+2)*32], x3=hT[(k+3)*32];
        float4 v0=*(const float4*)(w0+k);
        float4 v1=*(const float4*)(w1+k);
        float4 v2=*(const float4*)(w2+k);
        s0 += x0*v0.x + x1*v0.y + x2*v0.z + x3*v0.w;
        s1 += x0*v1.x + x1*v1.y + x2*v1.z + x3*v1.w;
        s2 += x0*v2.x + x1*v2.y + x2*v2.z + x3*v2.w;
      }
      float* red = sm;
      int ridx = ((jl*4 + kq)*32 + b)*4;
      red[ridx+0] = a0 + s0;
      red[ridx+1] = a1 + s1;
      red[ridx+2] = a2;
      red[ridx+3] = s2;
      __syncthreads();
      if (kq == 0){
        float P0=0.f, P1=0.f, P2=0.f, P3=0.f;
        #pragma unroll
        for (int q=0;q<4;q++){
          int ri = ((jl*4 + q)*32 + b)*4;
          P0 += red[ri+0]; P1 += red[ri+1]; P2 += red[ri+2]; P3 += red[ri+3];
        }
        const float* gi = GI0 + ((size_t)t*32 + b)*1536;
        float r = sigmoidf_(gi[jj]      + P0 + bhh[jj]);
        float z_ = sigmoidf_(gi[jj+512]  + P1 + bhh[jj+512]);
        float n = fast_tanh(gi[jj+1024] + P2 + r*(P3 + bhh[jj+1024]));
        float hold = h0cur[jj*32 + b];
        astore(h0nxt + jj*32 + b, (1.f - z_)*n + z_*hold);
      }
    }
    gbarH(ctr, mir, gctr, ef, myMir); ef++;

    // ---- P4
    {
      int b = tid & 31, kq = (tid >> 5) & 3, jl = tid >> 7;
      int jj = bid*2 + jl;
      const float* i0 = Wihr + (size_t)jj*512        + kq*128;
      const float* i1 = Wihr + (size_t)(jj+512)*512  + kq*128;
      const float* i2 = Wihr + (size_t)(jj+1024)*512 + kq*128;
      const float* xT = h0nxt + (size_t)(kq*128)*32 + b;
      float a0=0.f, a1=0.f, a2=0.f;
      #pragma unroll 8
      for (int k=0;k<128;k+=4){
        float x0=xT[(k+0)*32], x1=xT[(k+1)*32];
        float x2=xT[(k+2)*32], x3=xT[(k+3)*32];
        float4 v0=*(const float4*)(i0+k);
        float4 v1=*(const float4*)(i1+k);
        float4 v2=*(const float4*)(i2+k);
        a0 += x0*v0.x + x1*v0.y + x2*v0.z + x3*v0.w;
        a1 += x0*v1.x + x1*v1.y + x2*v1.z + x3*v1.w;
        a2 += x0*v2.x + x1*v2.y + x2*v2.z + x3*v2.w;
      }
      const float* w0 = Whh1 + (size_t)jj*512        + kq*128;
      const float* w1 = Whh1 + (size_t)(jj+512)*512  + kq*128;
      const float* w2 = Whh1 + (size_t)(jj+1024)*512 + kq*128;
      const float* hT = h1cur + (size_t)(kq*128)*32 + b;
      float s0=0.f, s1=0.f, s2=0.f;
      #pragma unroll 8
      for (int k=0;k<128;k+=4){
        float x0=hT[(k+0)*32], x1=hT[(k+1)*32];
        float x2=hT[(k+2)*32], x3=hT[(k+3)*32];
        float4 v0=*(const float4*)(w0+k);
        float4 v1=*(const float4*)(w1+k);
        float4 v2=*(const float4*)(w2+k);
        s0 += x0*v0.x + x1*v0.y + x2*v0.z + x3*v0.w;
        s1 += x0*v1.x + x1*v1.y + x2*v1.z + x3*v1.w;
        s2 += x0*v2.x + x1*v2.y + x2*v2.z + x3*v2.w;
      }
      float* red = sm;
      int ridx = ((jl*4 + kq)*32 + b)*4;
      red[ridx+0] = a0 + s0;
      red[ridx+1] = a1 + s1;
      red[ridx+2] = a2;
      red[ridx+3] = s2;
      __syncthreads();
      if (kq == 0){
        float P0=0.f, P1=0.f, P2=0.f, P3=0.f;
        #pragma unroll
        for (int q=0;q<4;q++){
          int ri = ((jl*4 + q)*32 + b)*4;
          P0 += red[ri+0]; P1 += red[ri+1]; P2 += red[ri+2]; P3 += red[ri+3];
        }
        float r = sigmoidf_(P0 + bih1[jj]      + bhh1[jj]);
        float z_ = sigmoidf_(P1 + bih1[jj+512]  + bhh1[jj+512]);
        float n = fast_tanh(P2 + bih1[jj+1024] + r*(P3 + bhh1[jj+1024]));
        float hold = h1cur[jj*32 + b];
        float hn = (1.f - z_)*n + z_*hold;
        astore(h1nxt + jj*32 + b, hn);
        Feat[((size_t)t*32 + b)*2560 + jj] = hn;
      }
    }
    gbarH(ctr, mir, gctr, ef, myMir); ef++;
  }
}

// zero the t=0 plane of out
__global__ __launch_bounds__(256) void zero_t0(float* __restrict__ out){
  int idx = blockIdx.x*256 + threadIdx.x;
  if (idx < 32*V){
    int b = idx / V, v = idx - b*V;
    out[(size_t)b*64*V + v] = 0.f;
  }
}

// ---------------- bf16 MFMA output GEMM (R13-exact) ----------------
__global__ __launch_bounds__(256) void out_gemm(
    const float* __restrict__ A,    // Feat [2016][2560]
    const float* __restrict__ Bw,   // out_W [32000][2560]
    const float* __restrict__ bias, // out_b [32000]
    float* __restrict__ out)        // [32][64][32000]
{
  __shared__ ushort As[4][129][8];
  __shared__ ushort Bs[4][129][8];
  int tid = threadIdx.x;
  int lane = tid & 63, wid = tid >> 6;
  // bijective XCD swizzle: 4000 % 8 == 0
  int orig = ((int)blockIdx.x & 7)*500 + ((int)blockIdx.x >> 3);
  int row0 = (orig & 15)*128, col0 = (orig >> 4)*128;
  int sr = tid >> 1;
  int s0 = (tid & 1) * 2;
  int sk = (tid & 1) * 16;
  int arow = row0 + sr; if (arow > 2015) arow = 2015;
  const float* Ap = A + (size_t)arow*2560 + sk;
  const float* Bp = Bw + (size_t)(col0 + sr)*2560 + sk;
  int wr = (wid >> 1)*64, wc = (wid & 1)*64;
  int fr = lane & 15, slot = lane >> 4;
  f32x4 acc[4][4];
  #pragma unroll
  for (int m=0;m<4;m++){
    #pragma unroll
    for (int n=0;n<4;n++) acc[m][n] = (f32x4){0.f,0.f,0.f,0.f};
  }
  for (int k0 = 0; k0 < 2560; k0 += 32){
    float4 a0 = *(const float4*)(Ap + k0);
    float4 a1 = *(const float4*)(Ap + k0 + 4);
    float4 a2 = *(const float4*)(Ap + k0 + 8);
    float4 a3 = *(const float4*)(Ap + k0 + 12);
    float4 b0 = *(const float4*)(Bp + k0);
    float4 b1 = *(const float4*)(Bp + k0 + 4);
    float4 b2 = *(const float4*)(Bp + k0 + 8);
    float4 b3 = *(const float4*)(Bp + k0 + 12);
    __syncthreads();
    uint4 ua, ua2, ub, ub2;
    ua.x  = cvtpk(a0.x, a0.y); ua.y  = cvtpk(a0.z, a0.w);
    ua.z  = cvtpk(a1.x, a1.y); ua.w  = cvtpk(a1.z, a1.w);
    ua2.x = cvtpk(a2.x, a2.y); ua2.y = cvtpk(a2.z, a2.w);
    ua2.z = cvtpk(a3.x, a3.y); ua2.w = cvtpk(a3.z, a3.w);
    ub.x  = cvtpk(b0.x, b0.y); ub.y  = cvtpk(b0.z, b0.w);
    ub.z  = cvtpk(b1.x, b1.y); ub.w  = cvtpk(b1.z, b1.w);
    ub2.x = cvtpk(b2.x, b2.y); ub2.y = cvtpk(b2.z, b2.w);
    ub2.z = cvtpk(b3.x, b3.y); ub2.w = cvtpk(b3.z, b3.w);
    *(uint4*)&As[s0  ][sr][0] = ua;
    *(uint4*)&As[s0+1][sr][0] = ua2;
    *(uint4*)&Bs[s0  ][sr][0] = ub;
    *(uint4*)&Bs[s0+1][sr][0] = ub2;
    __syncthreads();
    short8 af[4], bfr[4];
    #pragma unroll
    for (int m=0;m<4;m++) af[m]  = *(const short8*)&As[slot][wr + m*16 + fr][0];
    #pragma unroll
    for (int n=0;n<4;n++) bfr[n] = *(const short8*)&Bs[slot][wc + n*16 + fr][0];
    #pragma unroll
    for (int m=0;m<4;m++){
      #pragma unroll
      for (int n=0;n<4;n++)
        acc[m][n] = __builtin_amdgcn_mfma_f32_16x16x32_bf16(af[m], bfr[n], acc[m][n], 0, 0, 0);
    }
  }
  int cb = lane & 15, rb = (lane >> 4)*4;
  #pragma unroll
  for (int m=0;m<4;m++){
    #pragma unroll
    for (int n=0;n<4;n++){
      int c = col0 + wc + n*16 + cb;
      float bi = bias[c];
      #pragma unroll
      for (int j=0;j<4;j++){
        int r = row0 + wr + m*16 + rb + j;
        if (r < 2016){
          int bb = r & 31, tt = r >> 5;
          out[((size_t)bb*64 + tt + 1)*V + c] = acc[m][n][j] + bi;
        }
      }
    }
  }
}

extern "C" void kernel_launch(void* const* d_in, const int* in_sizes, int n_in,
                              void* d_out, int out_size, void* d_ws, size_t ws_size,
                              hipStream_t stream) {
  (void)in_sizes; (void)n_in; (void)out_size; (void)ws_size;
  const int*   ids    = (const int*)d_in[0];
  const int*   amask  = (const int*)d_in[1];
  const int*   labels = (const int*)d_in[2];
  const float* enc_emb= (const float*)d_in[3];
  const float* eWih   = (const float*)d_in[4];
  const float* eWhh   = (const float*)d_in[5];
  const float* ebih   = (const float*)d_in[6];
  const float* ebhh   = (const float*)d_in[7];
  const float* fcW    = (const float*)d_in[8];
  const float* fcb    = (const float*)d_in[9];
  const float* aW     = (const float*)d_in[10];
  const float* ab     = (const float*)d_in[11];
  const float* av     = (const float*)d_in[12];
  const float* dec_emb= (const float*)d_in[13];
  const float* dWih0  = (const float*)d_in[14];
  const float* dWihr  = (const float*)d_in[15];
  const float* dWhh   = (const float*)d_in[16];
  const float* dbih   = (const float*)d_in[17];
  const float* dbhh   = (const float*)d_in[18];
  const float* outW   = (const float*)d_in[19];
  const float* outb   = (const float*)d_in[20];
  float* out = (float*)d_out;

  // barrier zones: enc layer l zone (dir,bg) at bar + l*8192 + (dir*8+bg)*512
  // (16384 uints); dec at bar + 16384: ctr@0, mirrors@64..288,
  // bP zones@1024+bP*32, group ctrs@2048+g*32.
  uint*  bar = (uint*)d_ws;
  float* ws  = (float*)d_ws + 20480;
  float* X0  = ws;
  float* X1  = X0  + (size_t)4096*1024;
  float* ENC = X1  + (size_t)4096*1024;
  float* GIa = ENC + (size_t)4096*1024;
  float* GIb = GIa + (size_t)4096*1536;
  float* Eenc= GIb + (size_t)4096*1536;
  float* GI0 = Eenc+ (size_t)4096*512;
  float* Feat= GI0 + (size_t)2016*1536;
  float* hp  = Feat+ (size_t)2016*2560;
  float* hFa = hp;             float* hFb = hFa + 32*512;
  float* hBa = hFb + 32*512;   float* hBb = hBa + 32*512;
  // rotating decoder buffers live in the X0/X1 regions (dead by decoder time)
  float* wgtR  = X0;                          // 63 * 32768
  float* partR = X0 + (size_t)63*32768;       // 63 * 32768
  float* h0R   = X1;                          // 64 * 16384
  float* h1R   = X1 + (size_t)64*16384;       // 64 * 16384

  hipMemsetAsync(bar, 0, 20480*sizeof(uint), stream);

  // ---- encoder ----
  embed_enc<<<4096, 256, 0, stream>>>(ids, enc_emb, X0);
  for (int l = 0; l < NL; l++){
    const float* Xin = l ? X1 : X0;
    float* Xout = l ? ENC : X1;
    hipMemsetAsync(hFa, 0, 32*512*sizeof(float), stream);
    hipMemsetAsync(hBa, 0, 32*512*sizeof(float), stream);
    gemm_bf16<<<dim3(32,12),256,0,stream>>>(Xin, 1024, eWih + (size_t)(l*2+0)*1536*1024, 1024,
        ebih + (l*2+0)*1536, GIa, 1536, 4096, 1536, 1024);
    gemm_bf16<<<dim3(32,12),256,0,stream>>>(Xin, 1024, eWih + (size_t)(l*2+1)*1536*1024, 1024,
        ebih + (l*2+1)*1536, GIb, 1536, 4096, 1536, 1024);
    {
      const float* gia = GIa; const float* gib = GIb;
      const float* whhp = eWhh + (size_t)l*2*1536*512;
      const float* bhhp = ebhh + (size_t)l*2*1536;
      uint* eb = bar + (size_t)l*8192;
      void* args[] = {(void*)&gia, (void*)&gib, (void*)&whhp, (void*)&bhhp,
                      (void*)&amask, (void*)&hFa, (void*)&hFb, (void*)&hBa,
                      (void*)&hBb, (void*)&Xout, (void*)&eb};
      hipLaunchCooperativeKernel((const void*)enc_layer, dim3(256), dim3(256), args, 0, stream);
    }
  }
  // ---- decoder setup ----
  fc_init<<<128,256,0,stream>>>(hFa, hBa, fcW, fcb, h0R, h1R);
  gemm_bf16<<<dim3(32,4),256,0,stream>>>(ENC, 1024, aW + 512, 1536, ab, Eenc, 512, 4096, 512, 1024);
  embed_dec<<<2016,256,0,stream>>>(labels, dec_emb, Feat);
  gemm_bf16<<<dim3(16,12),256,0,stream>>>(Feat + 1536, 2560, dWih0, 2048, dbih, GI0, 1536, 2016, 1536, 1024);
  // ---- decoder loop ----
  {
    const float* encp = ENC; const float* eencp = Eenc; const float* gi0p = GI0;
    float* featp = Feat;
    uint* db = bar + 16384;
    void* args[] = {(void*)&encp, (void*)&eencp, (void*)&aW, (void*)&av,
                    (void*)&amask, (void*)&gi0p, (void*)&dWih0, (void*)&dWihr,
                    (void*)&dWhh, (void*)&dbih, (void*)&dbhh,
                    (void*)&h0R, (void*)&h1R, (void*)&wgtR, (void*)&partR,
                    (void*)&featp, (void*)&db};
    hipLaunchCooperativeKernel((const void*)dec_loop, dim3(256), dim3(256), args, 0, stream);
  }
  // ---- output ----
  zero_t0<<<4000,256,0,stream>>>(out);
  out_gemm<<<4000,256,0,stream>>>(Feat, outW, outb, out);
}